// Round 16
// baseline (279.770 us; speedup 1.0000x reference)
//
#include <hip/hip_runtime.h>

#define N_TOK 16384   // B*T = 8*2048
#define DIM   512
#define CBD   256     // codebook dim
#define CBS   8192    // codebook size

typedef short short8 __attribute__((ext_vector_type(8)));
typedef float f32x4 __attribute__((ext_vector_type(4)));

#define GLOAD16(g, l) __builtin_amdgcn_global_load_lds( \
    (const __attribute__((address_space(1))) void*)(g), \
    (__attribute__((address_space(3))) void*)(l), 16, 0, 0)

#define VMCNT(n) asm volatile("s_waitcnt vmcnt(" #n ")" ::: "memory")

__device__ inline unsigned short f2bf_rne(float f) {
    unsigned u = __float_as_uint(f);
    unsigned r = (u + 0x7FFFu + ((u >> 16) & 1u)) >> 16;
    return (unsigned short)r;
}
__device__ inline float bf2f(unsigned short h) { return __uint_as_float((unsigned)h << 16); }
__device__ inline short f2h(float f) {
    _Float16 h = (_Float16)f;           // v_cvt_f16_f32, RNE
    short r; __builtin_memcpy(&r, &h, 2); return r;
}
__device__ inline float h2f(short s) {
    _Float16 h; __builtin_memcpy(&h, &s, 2); return (float)h;
}

// ================= packing: 2-term split [hi(K) | lo(K)] per row ==============
template <int LOGK>
__global__ __launch_bounds__(256) void pack_w(const float* __restrict__ src, short* __restrict__ dst) {
    int e = blockIdx.x * 256 + threadIdx.x;
    int r = e >> LOGK, k = e & ((1 << LOGK) - 1);
    float v = src[e];
    unsigned short h = f2bf_rne(v);
    unsigned short l = f2bf_rne(v - bf2f(h));
    size_t base = (size_t)r << (LOGK + 1);
    dst[base + k] = (short)h;
    dst[base + (1 << LOGK) + k] = (short)l;
}

// fused: e_sq + 2-term bf16 pack (gemm_out) + f16 pack (score) + ||e-e16||^2
__global__ __launch_bounds__(256) void prep_embed(const float* __restrict__ embed,
                                                  float* __restrict__ esq,
                                                  short* __restrict__ epack,
                                                  short* __restrict__ e16,
                                                  float* __restrict__ denorm) {
    int wave = threadIdx.x >> 6, lane = threadIdx.x & 63;
    int c = (blockIdx.x << 2) + wave;
    float4 v = reinterpret_cast<const float4*>(embed + (size_t)c * CBD)[lane];
    short4 hs, ls, fs;
    {
        unsigned short h, l;
        h = f2bf_rne(v.x); l = f2bf_rne(v.x - bf2f(h)); hs.x = h; ls.x = l;
        h = f2bf_rne(v.y); l = f2bf_rne(v.y - bf2f(h)); hs.y = h; ls.y = l;
        h = f2bf_rne(v.z); l = f2bf_rne(v.z - bf2f(h)); hs.z = h; ls.z = l;
        h = f2bf_rne(v.w); l = f2bf_rne(v.w - bf2f(h)); hs.w = h; ls.w = l;
    }
    fs.x = f2h(v.x); fs.y = f2h(v.y); fs.z = f2h(v.z); fs.w = f2h(v.w);
    reinterpret_cast<short4*>(epack + (size_t)c * 512)[lane] = hs;
    reinterpret_cast<short4*>(epack + (size_t)c * 512 + 256)[lane] = ls;
    reinterpret_cast<short4*>(e16 + (size_t)c * 256)[lane] = fs;
    float s = v.x * v.x + v.y * v.y + v.z * v.z + v.w * v.w;
    float dx = v.x - h2f(fs.x), dy = v.y - h2f(fs.y);
    float dz = v.z - h2f(fs.z), dw = v.w - h2f(fs.w);
    float ds = dx * dx + dy * dy + dz * dz + dw * dw;
    #pragma unroll
    for (int m = 32; m; m >>= 1) { s += __shfl_xor(s, m, 64); ds += __shfl_xor(ds, m, 64); }
    if (!lane) { esq[c] = s; denorm[c] = ds; }
}

// ---- znorm2[r] = (||z16||, ||zf32 - z16||) ----
__global__ __launch_bounds__(256) void znorm_k(const float* __restrict__ zf32,
                                               const short* __restrict__ z16,
                                               float2* __restrict__ znorm2) {
    int wave = threadIdx.x >> 6, lane = threadIdx.x & 63;
    int r = blockIdx.x * 4 + wave;
    float4 v = reinterpret_cast<const float4*>(zf32 + (size_t)r * 256)[lane];
    short4 h = reinterpret_cast<const short4*>(z16 + (size_t)r * 256)[lane];
    float a = h2f(h.x), b = h2f(h.y), c = h2f(h.z), d = h2f(h.w);
    float s16 = a * a + b * b + c * c + d * d;
    float dx = v.x - a, dy = v.y - b, dz = v.z - c, dw = v.w - d;
    float ds = dx * dx + dy * dy + dz * dz + dw * dw;
    #pragma unroll
    for (int m = 32; m; m >>= 1) { s16 += __shfl_xor(s16, m, 64); ds += __shfl_xor(ds, m, 64); }
    if (!lane) znorm2[r] = make_float2(sqrtf(s16), sqrtf(ds));
}

// ---- maxe[0] = max_c ||e_c||, maxe[1] = max_c ||e_c - e16_c|| ----
__global__ __launch_bounds__(256) void maxe_k(const float* __restrict__ esq,
                                              const float* __restrict__ denorm,
                                              float* __restrict__ maxe) {
    float m = 0.f, md = 0.f;
    #pragma unroll
    for (int k = 0; k < 32; ++k) {
        m = fmaxf(m, esq[threadIdx.x + (k << 8)]);
        md = fmaxf(md, denorm[threadIdx.x + (k << 8)]);
    }
    #pragma unroll
    for (int s = 32; s; s >>= 1) {
        m = fmaxf(m, __shfl_xor(m, s, 64));
        md = fmaxf(md, __shfl_xor(md, s, 64));
    }
    __shared__ float w[4], wd[4];
    if (!(threadIdx.x & 63)) { w[threadIdx.x >> 6] = m; wd[threadIdx.x >> 6] = md; }
    __syncthreads();
    if (threadIdx.x == 0) {
        maxe[0] = sqrtf(fmaxf(fmaxf(w[0], w[1]), fmaxf(w[2], w[3])));
        maxe[1] = sqrtf(fmaxf(fmaxf(wd[0], wd[1]), fmaxf(wd[2], wd[3])));
    }
}

// ============ gemm_in: z = x@W_in^T + b_in, 4-term split-bf16, BM=64 BN=128 ===
__global__ __launch_bounds__(256, 3) void gemm_in_mfma(const short* __restrict__ xpk,
                                                       const short* __restrict__ wpk,
                                                       const float* __restrict__ b_in,
                                                       short* __restrict__ z16,
                                                       float* __restrict__ zf32) {
    __shared__ __align__(16) char smem[49152];
    const int tid = threadIdx.x;
    const int lane = tid & 63, wid = tid >> 6;
    const int l15 = lane & 15, rg = lane >> 4;
    const int bm = blockIdx.x << 6, bn = blockIdx.y << 7;
    const int g = tid & 7, rpb = tid >> 3;

    const char* xb = (const char*)xpk;
    const char* wb = (const char*)wpk;
    const int sw = ((g ^ (rpb & 7)) << 4);
    size_t aoff[2], boff[2][2];
    #pragma unroll
    for (int it = 0; it < 2; ++it)
        aoff[it] = (size_t)(bm + it * 32 + rpb) * 2048 + sw;
    #pragma unroll
    for (int it = 0; it < 4; ++it)
        boff[it >> 1][it & 1] = (size_t)(bn + it * 32 + rpb) * 2048 + sw;

    const int ax0 = ((rg ^ (l15 & 7)) << 4);
    const int ax1 = (((rg + 4) ^ (l15 & 7)) << 4);
    const char* aBase = smem + l15 * 128;
    const char* bBase = smem + 8192 + (wid * 32 + l15) * 128;

    f32x4 acc[4][2] = {};

#define GIN_STAGE(BUF, KT) do { \
    size_t aK = (size_t)(((((KT) >> 4) << 3) | ((KT) & 7))) * 128; \
    size_t bK = (size_t)((((((KT) >> 3) & 1) << 3) | ((KT) & 7))) * 128; \
    char* dA = smem + (BUF) * 24576 + (tid << 4); \
    char* dB = dA + 8192; \
    GLOAD16(xb + aoff[0] + aK, dA); \
    GLOAD16(xb + aoff[1] + aK, dA + 4096); \
    GLOAD16(wb + boff[0][0] + bK, dB); \
    GLOAD16(wb + boff[0][1] + bK, dB + 4096); \
    GLOAD16(wb + boff[1][0] + bK, dB + 8192); \
    GLOAD16(wb + boff[1][1] + bK, dB + 12288); } while (0)

    GIN_STAGE(0, 0);
    VMCNT(0);
    __syncthreads();
    #pragma unroll 1
    for (int kt = 0; kt < 32; ++kt) {
        const int buf = kt & 1;
        if (kt + 1 < 32) GIN_STAGE(buf ^ 1, kt + 1);
        const char* aB = aBase + buf * 24576;
        const char* bB = bBase + buf * 24576;
        #pragma unroll
        for (int ks = 0; ks < 2; ++ks) {
            int ax = ks ? ax1 : ax0;
            short8 aF[4], bF[2];
            #pragma unroll
            for (int mi = 0; mi < 4; ++mi) aF[mi] = *(const short8*)(aB + mi * 2048 + ax);
            #pragma unroll
            for (int ni = 0; ni < 2; ++ni) bF[ni] = *(const short8*)(bB + ni * 2048 + ax);
            #pragma unroll
            for (int mi = 0; mi < 4; ++mi)
                #pragma unroll
                for (int ni = 0; ni < 2; ++ni)
                    acc[mi][ni] = __builtin_amdgcn_mfma_f32_16x16x32_bf16(aF[mi], bF[ni], acc[mi][ni], 0, 0, 0);
        }
        VMCNT(0);
        __syncthreads();
    }
    float bb[2];
    #pragma unroll
    for (int ni = 0; ni < 2; ++ni) bb[ni] = b_in[bn + wid * 32 + ni * 16 + l15];
    #pragma unroll
    for (int mi = 0; mi < 4; ++mi)
        #pragma unroll
        for (int ni = 0; ni < 2; ++ni)
            #pragma unroll
            for (int j = 0; j < 4; ++j) {
                int r = bm + mi * 16 + rg * 4 + j;
                int c = bn + wid * 32 + ni * 16 + l15;
                float s = acc[mi][ni][j] + bb[ni];
                z16[(size_t)r * 256 + c] = f2h(s);
                zf32[(size_t)r * 256 + c] = s;
            }
}

// ===== score: A-in-registers (static idx), half-K B chunks, 2 blocks/CU.
// 256 thr (4 waves x 32 rows), block = 128 rows x 2048 cols (16 tiles of 128).
// B chunk = 128 cols x 256B (32KB), double-buffered (64KB LDS -> 2 blocks/CU).
// Each tile = two STATICALLY-UNROLLED phases (h=0 -> aF*[0..3], h=1 -> aF*[4..7]),
// so no runtime indexing (rule #20). Reg-only epilogue, transposed partials.
__global__ __launch_bounds__(256, 2) void score_mfma(const short* __restrict__ zpk,
                                                     const short* __restrict__ epk,
                                                     const float* __restrict__ esqg,
                                                     float4* __restrict__ partials) {
    __shared__ __align__(16) char smem[65536];   // B: 2 x 32KB (buf0=h0, buf1=h1)
    const int tid = threadIdx.x;
    const int lane = tid & 63, w = tid >> 6;     // 4 waves
    const int l15 = lane & 15, rg = lane >> 4;

    int flat = blockIdx.x;                       // 512 blocks
    int xcd = flat & 7, jb = flat >> 3;          // jb 0..63
    int g  = xcd >> 1;                           // col-group 0..3 (XCD pair)
    int bX = ((xcd & 1) << 6) + jb;              // 0..127 row-block (128 rows)
    const int bm = bX << 7;
    const int C0g = g << 11;                     // g*2048

    // ---- A fragments in registers (once), all indices compile-time ----
    const char* zb = (const char*)zpk;
    short8 aF0[8], aF1[8];
    #pragma unroll
    for (int ks = 0; ks < 8; ++ks) {
        aF0[ks] = *(const short8*)(zb + (size_t)(bm + w * 32 + l15) * 512 + ks * 64 + rg * 16);
        aF1[ks] = *(const short8*)(zb + (size_t)(bm + w * 32 + 16 + l15) * 512 + ks * 64 + rg * 16);
    }

    const char* eb = (const char*)epk;

    // B half-chunk (T, H): 128 cols x 256B. LDS unit u (16B): col=u>>4, slot=u&15.
    // Source pre-swizzled slot^(col&15) so linear gload_lds dest = swizzled image (T21).
#define SCB_STAGE(BUF, T, H) do { \
    _Pragma("unroll") for (int i_ = 0; i_ < 8; ++i_) { \
        int u_ = i_ * 256 + tid; \
        int col_ = u_ >> 4, slot_ = u_ & 15; \
        const char* s_ = eb + (size_t)(C0g + (T) * 128 + col_) * 512 + (H) * 256 \
                         + ((slot_ ^ (col_ & 15)) << 4); \
        GLOAD16(s_, smem + (BUF) * 32768 + u_ * 16); \
    } } while (0)

// one half-phase: read bF (8 ni) per ksLocal, 16 MFMA each. KS0 = h*4.
#define SC_PHASE(BUF, KS0) do { \
    const char* bB = smem + (BUF) * 32768; \
    _Pragma("unroll") for (int ksl = 0; ksl < 4; ++ksl) { \
        short8 bF[8]; \
        _Pragma("unroll") for (int ni = 0; ni < 8; ++ni) \
            bF[ni] = *(const short8*)(bB + (ni * 16 + l15) * 256 + \
                                      (((ksl * 4 + rg) ^ (l15 & 15)) << 4)); \
        _Pragma("unroll") for (int ni = 0; ni < 8; ++ni) { \
            acc0[ni] = __builtin_amdgcn_mfma_f32_16x16x32_f16(aF0[(KS0) + ksl], bF[ni], acc0[ni], 0, 0, 0); \
            acc1[ni] = __builtin_amdgcn_mfma_f32_16x16x32_f16(aF1[(KS0) + ksl], bF[ni], acc1[ni], 0, 0, 0); \
        } \
    } } while (0)

    f32x4 acc0[8] = {};
    f32x4 acc1[8] = {};

    SCB_STAGE(0, 0, 0);                          // tile0 h0 -> buf0
    VMCNT(0);
    __syncthreads();

    #pragma unroll 1
    for (int t = 0; t < 16; ++t) {
        // phase A: compute h0 from buf0; stage (t,h1) -> buf1
        SCB_STAGE(1, t, 1);
        SC_PHASE(0, 0);
        VMCNT(0);
        __syncthreads();
        // phase B: compute h1 from buf1; stage (t+1,h0) -> buf0; epilogue
        if (t < 15) SCB_STAGE(0, t + 1, 0);
        SC_PHASE(1, 4);
        {
            const int cb = C0g + t * 128 + l15;
            float esq8[8];
            #pragma unroll
            for (int ni = 0; ni < 8; ++ni) esq8[ni] = esqg[cb + ni * 16];
            #pragma unroll
            for (int mi = 0; mi < 2; ++mi)
                #pragma unroll
                for (int j2 = 0; j2 < 4; ++j2) {
                    float v1 = -3.4e38f, v2 = -3.4e38f;
                    int i1 = 0x7fffffff;
                    #pragma unroll
                    for (int ni = 0; ni < 8; ++ni) {
                        float s = fmaf(2.f, mi ? acc1[ni][j2] : acc0[ni][j2], -esq8[ni]);
                        int c = cb + ni * 16;
                        if (s > v1) { v2 = v1; v1 = s; i1 = c; }
                        else if (s > v2) v2 = s;
                    }
                    #pragma unroll
                    for (int m = 1; m < 16; m <<= 1) {
                        float ov1 = __shfl_xor(v1, m, 64);
                        int   oi1 = __shfl_xor(i1, m, 64);
                        float ov2 = __shfl_xor(v2, m, 64);
                        float nv2 = fmaxf(fmaxf(v2, ov2), fminf(v1, ov1));
                        if (ov1 > v1 || (ov1 == v1 && oi1 < i1)) { v1 = ov1; i1 = oi1; }
                        v2 = nv2;
                    }
                    if (l15 == 0) {
                        int row = bm + w * 32 + mi * 16 + rg * 4 + j2;
                        partials[(size_t)(g * 16 + t) * N_TOK + row] =
                            make_float4(v1, __int_as_float(i1), v2, 0.f);
                    }
                }
            #pragma unroll
            for (int ni = 0; ni < 8; ++ni) {
                acc0[ni] = (f32x4){0.f, 0.f, 0.f, 0.f};
                acc1[ni] = (f32x4){0.f, 0.f, 0.f, 0.f};
            }
        }
        VMCNT(0);
        __syncthreads();
    }
}

// -------- combine: global top-2 over 64 tiles + measured-norm rescue decision --
// partials layout: [tile][row]
__global__ __launch_bounds__(256) void combine(const float4* __restrict__ partials,
                                               const float2* __restrict__ znorm2,
                                               const float* __restrict__ maxe,
                                               int* __restrict__ idx, float* __restrict__ idxf,
                                               float* __restrict__ rescueT) {
    int sub = threadIdx.x & 63;
    int row = blockIdx.x * 4 + (threadIdx.x >> 6);
    float4 p = partials[(size_t)sub * N_TOK + row];
    float v1 = p.x; int i1 = __float_as_int(p.y); float v2 = p.z;
    #pragma unroll
    for (int m = 1; m < 64; m <<= 1) {
        float ov1 = __shfl_xor(v1, m, 64);
        int   oi1 = __shfl_xor(i1, m, 64);
        float ov2 = __shfl_xor(v2, m, 64);
        float nv2 = fmaxf(fmaxf(v2, ov2), fminf(v1, ov1));
        if (ov1 > v1 || (ov1 == v1 && oi1 < i1)) { v1 = ov1; i1 = oi1; }
        v2 = nv2;
    }
    if (sub == 0) {
        float2 zn = znorm2[row];
        float thr = fmaf(2.1f, zn.y * maxe[0] + zn.x * maxe[1], 0.02f);
        idx[row] = i1;
        idxf[row] = (float)i1;
        rescueT[row] = (v1 - v2 <= thr) ? (v1 - thr) : 3.0e38f;
    }
}

// ---- exact rescue: 16 lanes per code (coalesced), f32 rescan of candidate tiles
__global__ __launch_bounds__(256) void rescue(const float* __restrict__ zf32,
                                              const float* __restrict__ embed,
                                              const float* __restrict__ esq,
                                              const float4* __restrict__ partials,
                                              const float* __restrict__ rescueT,
                                              int* __restrict__ idx, float* __restrict__ idxf) {
    int row = blockIdx.x;
    float t = rescueT[row];
    if (t > 1.0e38f) return;
    __shared__ __align__(16) float zrow[256];
    __shared__ float gv[16];
    __shared__ int   gi[16];
    const int tid = threadIdx.x;
    const int grp = tid >> 4, ln = tid & 15;
    zrow[tid] = zf32[(size_t)row * 256 + tid];
    __syncthreads();
    const float4* zr = (const float4*)zrow;
    float bv = -3.4e38f; int bi = 0x7fffffff;
    for (int nt = 0; nt < 64; ++nt) {
        if (partials[(size_t)nt * N_TOK + row].x < t) continue;  // block-uniform
        #pragma unroll 1
        for (int it = 0; it < 8; ++it) {
            int c = nt * 128 + it * 16 + grp;
            const float4* er = (const float4*)(embed + (size_t)c * 256);
            float d = 0.f;
            #pragma unroll
            for (int q = 0; q < 4; ++q) {
                float4 e4 = er[q * 16 + ln];
                float4 z4 = zr[q * 16 + ln];
                d = fmaf(e4.x, z4.x, d); d = fmaf(e4.y, z4.y, d);
                d = fmaf(e4.z, z4.z, d); d = fmaf(e4.w, z4.w, d);
            }
            #pragma unroll
            for (int m = 1; m < 16; m <<= 1) d += __shfl_xor(d, m, 64);
            if (ln == 0) {
                float s = 2.f * d - esq[c];
                if (s > bv || (s == bv && c < bi)) { bv = s; bi = c; }
            }
        }
    }
    if (ln == 0) { gv[grp] = bv; gi[grp] = bi; }
    __syncthreads();
    if (tid == 0) {
        float v = gv[0]; int i = gi[0];
        #pragma unroll
        for (int k = 1; k < 16; ++k)
            if (gv[k] > v || (gv[k] == v && gi[k] < i)) { v = gv[k]; i = gi[k]; }
        idx[row] = i; idxf[row] = (float)i;
    }
}

// ====== gemm_out: out = embed[idx]@W_out^T + b_out, 4-term, BM=128 BN=128 =====
__global__ __launch_bounds__(256, 2) void gemm_out_mfma(const short* __restrict__ epk,
                                                        const short* __restrict__ wpk,
                                                        const int* __restrict__ idx,
                                                        const float* __restrict__ b_out,
                                                        float* __restrict__ out) {
    __shared__ __align__(16) char smem[65536];
    const int tid = threadIdx.x;
    const int lane = tid & 63, wid = tid >> 6;
    const int wr = wid >> 1, wc = wid & 1;
    const int l15 = lane & 15, rg = lane >> 4;
    const int bm = blockIdx.x << 7, bn = blockIdx.y << 7;
    const int g = tid & 7, rpb = tid >> 3;

    const char* ebp = (const char*)epk;
    const char* wb = (const char*)wpk;
    const int sw = ((g ^ (rpb & 7)) << 4);
    size_t aoff[4], boff[4];
    #pragma unroll
    for (int it = 0; it < 4; ++it) {
        int c = idx[bm + it * 32 + rpb];
        aoff[it] = (size_t)c * 1024 + sw;
        boff[it] = (size_t)(bn + it * 32 + rpb) * 1024 + sw;
    }

    const int ax0 = ((rg ^ (l15 & 7)) << 4);
    const int ax1 = (((rg + 4) ^ (l15 & 7)) << 4);
    const char* aBase = smem + (wr * 64 + l15) * 128;
    const char* bBase = smem + 16384 + (wc * 64 + l15) * 128;

    f32x4 acc[4][4] = {};

#define GOUT_STAGE(BUF, KT) do { \
    size_t aK = (size_t)((((KT) & 3) | (((KT) >> 3) << 2))) * 128; \
    size_t bK = (size_t)((KT) & 7) * 128; \
    char* dA = smem + (BUF) * 32768 + (tid << 4); \
    char* dB = dA + 16384; \
    _Pragma("unroll") for (int it_ = 0; it_ < 4; ++it_) { \
        GLOAD16(ebp + aoff[it_] + aK, dA + it_ * 4096); \
        GLOAD16(wb + boff[it_] + bK, dB + it_ * 4096); } } while (0)

    GOUT_STAGE(0, 0);
    VMCNT(0);
    __syncthreads();
    #pragma unroll 1
    for (int kt = 0; kt < 16; ++kt) {
        const int buf = kt & 1;
        if (kt + 1 < 16) GOUT_STAGE(buf ^ 1, kt + 1);
        const char* aB = aBase + buf * 32768;
        const char* bB = bBase + buf * 32768;
        #pragma unroll
        for (int ks = 0; ks < 2; ++ks) {
            int ax = ks ? ax1 : ax0;
            short8 aF[4], bF[4];
            #pragma unroll
            for (int mi = 0; mi < 4; ++mi) aF[mi] = *(const short8*)(aB + mi * 2048 + ax);
            #pragma unroll
            for (int ni = 0; ni < 4; ++ni) bF[ni] = *(const short8*)(bB + ni * 2048 + ax);
            #pragma unroll
            for (int mi = 0; mi < 4; ++mi)
                #pragma unroll
                for (int ni = 0; ni < 4; ++ni)
                    acc[mi][ni] = __builtin_amdgcn_mfma_f32_16x16x32_bf16(aF[mi], bF[ni], acc[mi][ni], 0, 0, 0);
        }
        VMCNT(0);
        __syncthreads();
    }
    float bb[4];
    #pragma unroll
    for (int ni = 0; ni < 4; ++ni) bb[ni] = b_out[bn + wc * 64 + ni * 16 + l15];
    #pragma unroll
    for (int mi = 0; mi < 4; ++mi)
        #pragma unroll
        for (int ni = 0; ni < 4; ++ni)
            #pragma unroll
            for (int j = 0; j < 4; ++j) {
                int r = bm + wr * 64 + mi * 16 + rg * 4 + j;
                int c = bn + wc * 64 + ni * 16 + l15;
                out[(size_t)r * 512 + c] = acc[mi][ni][j] + bb[ni];
            }
}

// =================== fallback f32 path (ws too small) =========================
__global__ __launch_bounds__(256) void esq_kernel(const float* __restrict__ embed,
                                                  float* __restrict__ esq) {
    int wave = threadIdx.x >> 6, lane = threadIdx.x & 63;
    int c = (blockIdx.x << 2) + wave;
    float4 v = reinterpret_cast<const float4*>(embed + (size_t)c * CBD)[lane];
    float s = v.x * v.x + v.y * v.y + v.z * v.z + v.w * v.w;
    #pragma unroll
    for (int m = 32; m; m >>= 1) s += __shfl_xor(s, m, 64);
    if (!lane) esq[c] = s;
}

template <bool GATHER>
__global__ __launch_bounds__(256) void gemm_nt(const float* __restrict__ A,
                                               const float* __restrict__ B,
                                               const float* __restrict__ bias,
                                               const int* __restrict__ gather,
                                               float* __restrict__ C,
                                               int M, int N, int K) {
    __shared__ __align__(16) float sA[64][68];
    __shared__ __align__(16) float sB[64][68];
    const int tid = threadIdx.x;
    const int tx = tid & 15, ty = tid >> 4;
    const int bm = blockIdx.x << 6, bn = blockIdx.y << 6;
    float acc[4][4] = {};
    for (int k0 = 0; k0 < K; k0 += 64) {
        #pragma unroll
        for (int i = 0; i < 4; ++i) {
            int f = tid + (i << 8);
            int m = f >> 4;
            int k4 = (f & 15) << 2;
            long arow = bm + m;
            if (GATHER) arow = gather[arow];
            float4 v = *reinterpret_cast<const float4*>(A + arow * K + k0 + k4);
            sA[k4 + 0][m] = v.x; sA[k4 + 1][m] = v.y;
            sA[k4 + 2][m] = v.z; sA[k4 + 3][m] = v.w;
            float4 w = *reinterpret_cast<const float4*>(B + (long)(bn + m) * K + k0 + k4);
            sB[k4 + 0][m] = w.x; sB[k4 + 1][m] = w.y;
            sB[k4 + 2][m] = w.z; sB[k4 + 3][m] = w.w;
        }
        __syncthreads();
        #pragma unroll
        for (int kk = 0; kk < 64; ++kk) {
            float4 a = *reinterpret_cast<const float4*>(&sA[kk][ty << 2]);
            float4 b = *reinterpret_cast<const float4*>(&sB[kk][tx << 2]);
            float av[4] = {a.x, a.y, a.z, a.w};
            float bv[4] = {b.x, b.y, b.z, b.w};
            #pragma unroll
            for (int i = 0; i < 4; ++i)
                #pragma unroll
                for (int j = 0; j < 4; ++j)
                    acc[i][j] = fmaf(av[i], bv[j], acc[i][j]);
        }
        __syncthreads();
    }
    #pragma unroll
    for (int i = 0; i < 4; ++i) {
        long m = bm + (ty << 2) + i;
        #pragma unroll
        for (int j = 0; j < 4; ++j) {
            int n = bn + (tx << 2) + j;
            C[m * N + n] = acc[i][j] + bias[n];
        }
    }
}

__global__ __launch_bounds__(256) void score_argmax(const float* __restrict__ z,
                                                    const float* __restrict__ embed,
                                                    const float* __restrict__ esq,
                                                    int* __restrict__ idx_out,
                                                    float* __restrict__ idx_f32) {
    __shared__ __align__(16) float sZ[64][68];
    __shared__ __align__(16) float sE[64][68];
    const int tid = threadIdx.x;
    const int tx = tid & 15, ty = tid >> 4;
    const int bm = blockIdx.x << 6;
    float best[4];
    int bidx[4];
    #pragma unroll
    for (int i = 0; i < 4; ++i) { best[i] = -3.4e38f; bidx[i] = 0; }
    for (int ct = 0; ct < CBS; ct += 64) {
        float acc[4][4] = {};
        for (int k0 = 0; k0 < CBD; k0 += 64) {
            #pragma unroll
            for (int i = 0; i < 4; ++i) {
                int f = tid + (i << 8);
                int m = f >> 4;
                int k4 = (f & 15) << 2;
                float4 v = *reinterpret_cast<const float4*>(z + (long)(bm + m) * CBD + k0 + k4);
                sZ[k4 + 0][m] = v.x; sZ[k4 + 1][m] = v.y;
                sZ[k4 + 2][m] = v.z; sZ[k4 + 3][m] = v.w;
                float4 w = *reinterpret_cast<const float4*>(embed + (long)(ct + m) * CBD + k0 + k4);
                sE[k4 + 0][m] = w.x; sE[k4 + 1][m] = w.y;
                sE[k4 + 2][m] = w.z; sE[k4 + 3][m] = w.w;
            }
            __syncthreads();
            #pragma unroll
            for (int kk = 0; kk < 64; ++kk) {
                float4 a = *reinterpret_cast<const float4*>(&sZ[kk][ty << 2]);
                float4 b = *reinterpret_cast<const float4*>(&sE[kk][tx << 2]);
                float av[4] = {a.x, a.y, a.z, a.w};
                float bv[4] = {b.x, b.y, b.z, b.w};
                #pragma unroll
                for (int i = 0; i < 4; ++i)
                    #pragma unroll
                    for (int j = 0; j < 4; ++j)
                        acc[i][j] = fmaf(av[i], bv[j], acc[i][j]);
            }
            __syncthreads();
        }
        #pragma unroll
        for (int j = 0; j < 4; ++j) {
            int c = ct + (tx << 2) + j;
            float eq = esq[c];
            #pragma unroll
            for (int i = 0; i < 4; ++i) {
                float s = 2.0f * acc[i][j] - eq;
                if (s > best[i] || (s == best[i] && c < bidx[i])) { best[i] = s; bidx[i] = c; }
            }
        }
    }
    #pragma unroll
    for (int i = 0; i < 4; ++i) {
        float b = best[i];
        int bi = bidx[i];
        #pragma unroll
        for (int m = 1; m < 16; m <<= 1) {
            float ob = __shfl_xor(b, m, 64);
            int oi = __shfl_xor(bi, m, 64);
            if (ob > b || (ob == b && oi < bi)) { b = ob; bi = oi; }
        }
        if (tx == 0) {
            int row = bm + (ty << 2) + i;
            idx_out[row] = bi;
            idx_f32[row] = (float)bi;
        }
    }
}

extern "C" void kernel_launch(void* const* d_in, const int* in_sizes, int n_in,
                              void* d_out, int out_size, void* d_ws, size_t ws_size,
                              hipStream_t stream) {
    const float* x     = (const float*)d_in[0];
    const float* embed = (const float*)d_in[1];
    const float* W_in  = (const float*)d_in[2];
    const float* b_in  = (const float*)d_in[3];
    const float* W_out = (const float*)d_in[4];
    const float* b_out = (const float*)d_in[5];

    float* out_idx = (float*)d_out;              // [16384] indices as float
    float* out     = (float*)d_out + N_TOK;      // [16384,512]

    // workspace layout (main path). partials (16MB) aliases xpack (dead after gemm_in).
    char* ws = (char*)d_ws;
    float*  esq      = (float*)ws;                                   // 32KB
    float*  rescueT  = (float*)(ws + 32768);                         // 64KB
    int*    idx      = (int*)(ws + 98304);                           // 64KB
    float2* znorm2   = (float2*)(ws + 163840);                       // 128KB
    float*  denorm   = (float*)(ws + 294912);                        // 32KB
    float*  maxe     = (float*)(ws + 327680);                        // 256B
    short*  xpack    = (short*)(ws + 327936);                        // 33.55MB
    float4* partials = (float4*)(ws + 327936);                       // 16MB (alias)
    float*  zf32     = (float*)(ws + 327936 + 33554432);             // 16.78MB
    short*  z16      = (short*)((char*)zf32 + 16777216);             // 8.39MB
    short*  e16      = z16 + (size_t)N_TOK * 256;                    // 4.19MB
    short*  epack    = e16 + (size_t)CBS * 256;                      // 8.39MB
    short*  winpk    = epack + (size_t)CBS * 512;                    // 0.52MB
    short*  wopk     = winpk + (size_t)CBD * 1024;                   // 0.52MB
    size_t need = (size_t)((char*)(wopk + (size_t)DIM * 512) - ws);

    if (ws_size >= need) {
        pack_w<9><<<(N_TOK * DIM) / 256, 256, 0, stream>>>(x, xpack);
        pack_w<9><<<(CBD * DIM) / 256, 256, 0, stream>>>(W_in, winpk);
        pack_w<8><<<(DIM * CBD) / 256, 256, 0, stream>>>(W_out, wopk);
        prep_embed<<<CBS / 4, 256, 0, stream>>>(embed, esq, epack, e16, denorm);
        maxe_k<<<1, 256, 0, stream>>>(esq, denorm, maxe);
        // z = x@W_in^T + b_in (4-term MFMA) -> z16 (f16) + zf32 (exact)
        gemm_in_mfma<<<dim3(N_TOK / 64, 2), 256, 0, stream>>>(xpack, winpk, b_in, z16, zf32);
        znorm_k<<<N_TOK / 4, 256, 0, stream>>>(zf32, z16, znorm2);
        // fp16 scores: A-in-reg, static half-K phases, 2 blocks/CU
        score_mfma<<<512, 256, 0, stream>>>(z16, e16, esq, partials);
        // combine -> idx + measured-norm rescue thresholds
        combine<<<N_TOK / 4, 256, 0, stream>>>(partials, znorm2, maxe, idx, out_idx, rescueT);
        // exact rescue (zf32-based; coalesced 16-lane-per-code scan)
        rescue<<<N_TOK, 256, 0, stream>>>(zf32, embed, esq, partials, rescueT, idx, out_idx);
        // out = embed[idx]@W_out^T + b_out
        gemm_out_mfma<<<dim3(N_TOK / 128, 4), 256, 0, stream>>>(epack, wopk, idx, b_out, out);
    } else {
        float* z   = (float*)d_ws;
        float* es  = z + (size_t)N_TOK * CBD;
        int*   id  = (int*)(es + CBS);
        gemm_nt<false><<<dim3(N_TOK / 64, CBD / 64), 256, 0, stream>>>(
            x, W_in, b_in, nullptr, z, N_TOK, CBD, DIM);
        esq_kernel<<<CBS / 4, 256, 0, stream>>>(embed, es);
        score_argmax<<<N_TOK / 64, 256, 0, stream>>>(z, embed, es, id, out_idx);
        gemm_nt<true><<<dim3(N_TOK / 64, DIM / 64), 256, 0, stream>>>(
            embed, W_out, b_out, id, out, N_TOK, DIM, CBD);
    }
}

// Round 17
// 245.493 us; speedup vs baseline: 1.1396x; 1.1396x over previous
//
#include <hip/hip_runtime.h>

#define N_TOK 16384   // B*T = 8*2048
#define DIM   512
#define CBD   256     // codebook dim
#define CBS   8192    // codebook size

typedef short short8 __attribute__((ext_vector_type(8)));
typedef float f32x4 __attribute__((ext_vector_type(4)));

#define GLOAD16(g, l) __builtin_amdgcn_global_load_lds( \
    (const __attribute__((address_space(1))) void*)(g), \
    (__attribute__((address_space(3))) void*)(l), 16, 0, 0)

#define VMCNT(n) asm volatile("s_waitcnt vmcnt(" #n ")" ::: "memory")

__device__ inline unsigned short f2bf_rne(float f) {
    unsigned u = __float_as_uint(f);
    unsigned r = (u + 0x7FFFu + ((u >> 16) & 1u)) >> 16;
    return (unsigned short)r;
}
__device__ inline float bf2f(unsigned short h) { return __uint_as_float((unsigned)h << 16); }
__device__ inline short f2h(float f) {
    _Float16 h = (_Float16)f;           // v_cvt_f16_f32, RNE
    short r; __builtin_memcpy(&r, &h, 2); return r;
}
__device__ inline float h2f(short s) {
    _Float16 h; __builtin_memcpy(&h, &s, 2); return (float)h;
}

// ================= packing: 2-term split [hi(K) | lo(K)] per row ==============
template <int LOGK>
__global__ __launch_bounds__(256) void pack_w(const float* __restrict__ src, short* __restrict__ dst) {
    int e = blockIdx.x * 256 + threadIdx.x;
    int r = e >> LOGK, k = e & ((1 << LOGK) - 1);
    float v = src[e];
    unsigned short h = f2bf_rne(v);
    unsigned short l = f2bf_rne(v - bf2f(h));
    size_t base = (size_t)r << (LOGK + 1);
    dst[base + k] = (short)h;
    dst[base + (1 << LOGK) + k] = (short)l;
}

// fused: e_sq + 2-term bf16 pack (gemm_out) + f16 pack (score) + ||e-e16||^2
__global__ __launch_bounds__(256) void prep_embed(const float* __restrict__ embed,
                                                  float* __restrict__ esq,
                                                  short* __restrict__ epack,
                                                  short* __restrict__ e16,
                                                  float* __restrict__ denorm) {
    int wave = threadIdx.x >> 6, lane = threadIdx.x & 63;
    int c = (blockIdx.x << 2) + wave;
    float4 v = reinterpret_cast<const float4*>(embed + (size_t)c * CBD)[lane];
    short4 hs, ls, fs;
    {
        unsigned short h, l;
        h = f2bf_rne(v.x); l = f2bf_rne(v.x - bf2f(h)); hs.x = h; ls.x = l;
        h = f2bf_rne(v.y); l = f2bf_rne(v.y - bf2f(h)); hs.y = h; ls.y = l;
        h = f2bf_rne(v.z); l = f2bf_rne(v.z - bf2f(h)); hs.z = h; ls.z = l;
        h = f2bf_rne(v.w); l = f2bf_rne(v.w - bf2f(h)); hs.w = h; ls.w = l;
    }
    fs.x = f2h(v.x); fs.y = f2h(v.y); fs.z = f2h(v.z); fs.w = f2h(v.w);
    reinterpret_cast<short4*>(epack + (size_t)c * 512)[lane] = hs;
    reinterpret_cast<short4*>(epack + (size_t)c * 512 + 256)[lane] = ls;
    reinterpret_cast<short4*>(e16 + (size_t)c * 256)[lane] = fs;
    float s = v.x * v.x + v.y * v.y + v.z * v.z + v.w * v.w;
    float dx = v.x - h2f(fs.x), dy = v.y - h2f(fs.y);
    float dz = v.z - h2f(fs.z), dw = v.w - h2f(fs.w);
    float ds = dx * dx + dy * dy + dz * dz + dw * dw;
    #pragma unroll
    for (int m = 32; m; m >>= 1) { s += __shfl_xor(s, m, 64); ds += __shfl_xor(ds, m, 64); }
    if (!lane) { esq[c] = s; denorm[c] = ds; }
}

// ---- znorm2[r] = (||z16||, ||zf32 - z16||) ----
__global__ __launch_bounds__(256) void znorm_k(const float* __restrict__ zf32,
                                               const short* __restrict__ z16,
                                               float2* __restrict__ znorm2) {
    int wave = threadIdx.x >> 6, lane = threadIdx.x & 63;
    int r = blockIdx.x * 4 + wave;
    float4 v = reinterpret_cast<const float4*>(zf32 + (size_t)r * 256)[lane];
    short4 h = reinterpret_cast<const short4*>(z16 + (size_t)r * 256)[lane];
    float a = h2f(h.x), b = h2f(h.y), c = h2f(h.z), d = h2f(h.w);
    float s16 = a * a + b * b + c * c + d * d;
    float dx = v.x - a, dy = v.y - b, dz = v.z - c, dw = v.w - d;
    float ds = dx * dx + dy * dy + dz * dz + dw * dw;
    #pragma unroll
    for (int m = 32; m; m >>= 1) { s16 += __shfl_xor(s16, m, 64); ds += __shfl_xor(ds, m, 64); }
    if (!lane) znorm2[r] = make_float2(sqrtf(s16), sqrtf(ds));
}

// ---- maxe[0] = max_c ||e_c||, maxe[1] = max_c ||e_c - e16_c|| ----
__global__ __launch_bounds__(256) void maxe_k(const float* __restrict__ esq,
                                              const float* __restrict__ denorm,
                                              float* __restrict__ maxe) {
    float m = 0.f, md = 0.f;
    #pragma unroll
    for (int k = 0; k < 32; ++k) {
        m = fmaxf(m, esq[threadIdx.x + (k << 8)]);
        md = fmaxf(md, denorm[threadIdx.x + (k << 8)]);
    }
    #pragma unroll
    for (int s = 32; s; s >>= 1) {
        m = fmaxf(m, __shfl_xor(m, s, 64));
        md = fmaxf(md, __shfl_xor(md, s, 64));
    }
    __shared__ float w[4], wd[4];
    if (!(threadIdx.x & 63)) { w[threadIdx.x >> 6] = m; wd[threadIdx.x >> 6] = md; }
    __syncthreads();
    if (threadIdx.x == 0) {
        maxe[0] = sqrtf(fmaxf(fmaxf(w[0], w[1]), fmaxf(w[2], w[3])));
        maxe[1] = sqrtf(fmaxf(fmaxf(wd[0], wd[1]), fmaxf(wd[2], wd[3])));
    }
}

// ============ gemm_in: z = x@W_in^T + b_in, 4-term split-bf16, BM=64 BN=128 ===
__global__ __launch_bounds__(256, 3) void gemm_in_mfma(const short* __restrict__ xpk,
                                                       const short* __restrict__ wpk,
                                                       const float* __restrict__ b_in,
                                                       short* __restrict__ z16,
                                                       float* __restrict__ zf32) {
    __shared__ __align__(16) char smem[49152];
    const int tid = threadIdx.x;
    const int lane = tid & 63, wid = tid >> 6;
    const int l15 = lane & 15, rg = lane >> 4;
    const int bm = blockIdx.x << 6, bn = blockIdx.y << 7;
    const int g = tid & 7, rpb = tid >> 3;

    const char* xb = (const char*)xpk;
    const char* wb = (const char*)wpk;
    const int sw = ((g ^ (rpb & 7)) << 4);
    size_t aoff[2], boff[2][2];
    #pragma unroll
    for (int it = 0; it < 2; ++it)
        aoff[it] = (size_t)(bm + it * 32 + rpb) * 2048 + sw;
    #pragma unroll
    for (int it = 0; it < 4; ++it)
        boff[it >> 1][it & 1] = (size_t)(bn + it * 32 + rpb) * 2048 + sw;

    const int ax0 = ((rg ^ (l15 & 7)) << 4);
    const int ax1 = (((rg + 4) ^ (l15 & 7)) << 4);
    const char* aBase = smem + l15 * 128;
    const char* bBase = smem + 8192 + (wid * 32 + l15) * 128;

    f32x4 acc[4][2] = {};

#define GIN_STAGE(BUF, KT) do { \
    size_t aK = (size_t)(((((KT) >> 4) << 3) | ((KT) & 7))) * 128; \
    size_t bK = (size_t)((((((KT) >> 3) & 1) << 3) | ((KT) & 7))) * 128; \
    char* dA = smem + (BUF) * 24576 + (tid << 4); \
    char* dB = dA + 8192; \
    GLOAD16(xb + aoff[0] + aK, dA); \
    GLOAD16(xb + aoff[1] + aK, dA + 4096); \
    GLOAD16(wb + boff[0][0] + bK, dB); \
    GLOAD16(wb + boff[0][1] + bK, dB + 4096); \
    GLOAD16(wb + boff[1][0] + bK, dB + 8192); \
    GLOAD16(wb + boff[1][1] + bK, dB + 12288); } while (0)

    GIN_STAGE(0, 0);
    VMCNT(0);
    __syncthreads();
    #pragma unroll 1
    for (int kt = 0; kt < 32; ++kt) {
        const int buf = kt & 1;
        if (kt + 1 < 32) GIN_STAGE(buf ^ 1, kt + 1);
        const char* aB = aBase + buf * 24576;
        const char* bB = bBase + buf * 24576;
        #pragma unroll
        for (int ks = 0; ks < 2; ++ks) {
            int ax = ks ? ax1 : ax0;
            short8 aF[4], bF[2];
            #pragma unroll
            for (int mi = 0; mi < 4; ++mi) aF[mi] = *(const short8*)(aB + mi * 2048 + ax);
            #pragma unroll
            for (int ni = 0; ni < 2; ++ni) bF[ni] = *(const short8*)(bB + ni * 2048 + ax);
            #pragma unroll
            for (int mi = 0; mi < 4; ++mi)
                #pragma unroll
                for (int ni = 0; ni < 2; ++ni)
                    acc[mi][ni] = __builtin_amdgcn_mfma_f32_16x16x32_bf16(aF[mi], bF[ni], acc[mi][ni], 0, 0, 0);
        }
        VMCNT(0);
        __syncthreads();
    }
    float bb[2];
    #pragma unroll
    for (int ni = 0; ni < 2; ++ni) bb[ni] = b_in[bn + wid * 32 + ni * 16 + l15];
    #pragma unroll
    for (int mi = 0; mi < 4; ++mi)
        #pragma unroll
        for (int ni = 0; ni < 2; ++ni)
            #pragma unroll
            for (int j = 0; j < 4; ++j) {
                int r = bm + mi * 16 + rg * 4 + j;
                int c = bn + wid * 32 + ni * 16 + l15;
                float s = acc[mi][ni][j] + bb[ni];
                z16[(size_t)r * 256 + c] = f2h(s);
                zf32[(size_t)r * 256 + c] = s;
            }
}

// ===== score: A-in-registers (static idx), half-K B chunks, 2 blocks/CU.
// Running per-lane top-2 across all 16 tiles (no per-tile triple merge);
// per-tile MAX-only shfl reduce -> tmax[tile][row] (rescue screening);
// ONE full (v1,i1,v2) merge per block -> cand[g][row].
__global__ __launch_bounds__(256, 2) void score_mfma(const short* __restrict__ zpk,
                                                     const short* __restrict__ epk,
                                                     const float* __restrict__ esqg,
                                                     float* __restrict__ tmax,
                                                     float4* __restrict__ cand) {
    __shared__ __align__(16) char smem[65536];   // B: 2 x 32KB (buf0=h0, buf1=h1)
    const int tid = threadIdx.x;
    const int lane = tid & 63, w = tid >> 6;     // 4 waves
    const int l15 = lane & 15, rg = lane >> 4;

    int flat = blockIdx.x;                       // 512 blocks
    int xcd = flat & 7, jb = flat >> 3;          // jb 0..63
    int g  = xcd >> 1;                           // col-group 0..3 (XCD pair)
    int bX = ((xcd & 1) << 6) + jb;              // 0..127 row-block (128 rows)
    const int bm = bX << 7;
    const int C0g = g << 11;                     // g*2048

    // ---- A fragments in registers (once), all indices compile-time ----
    const char* zb = (const char*)zpk;
    short8 aF0[8], aF1[8];
    #pragma unroll
    for (int ks = 0; ks < 8; ++ks) {
        aF0[ks] = *(const short8*)(zb + (size_t)(bm + w * 32 + l15) * 512 + ks * 64 + rg * 16);
        aF1[ks] = *(const short8*)(zb + (size_t)(bm + w * 32 + 16 + l15) * 512 + ks * 64 + rg * 16);
    }

    const char* eb = (const char*)epk;

#define SCB_STAGE(BUF, T, H) do { \
    _Pragma("unroll") for (int i_ = 0; i_ < 8; ++i_) { \
        int u_ = i_ * 256 + tid; \
        int col_ = u_ >> 4, slot_ = u_ & 15; \
        const char* s_ = eb + (size_t)(C0g + (T) * 128 + col_) * 512 + (H) * 256 \
                         + ((slot_ ^ (col_ & 15)) << 4); \
        GLOAD16(s_, smem + (BUF) * 32768 + u_ * 16); \
    } } while (0)

#define SC_PHASE(BUF, KS0) do { \
    const char* bB = smem + (BUF) * 32768; \
    _Pragma("unroll") for (int ksl = 0; ksl < 4; ++ksl) { \
        short8 bF[8]; \
        _Pragma("unroll") for (int ni = 0; ni < 8; ++ni) \
            bF[ni] = *(const short8*)(bB + (ni * 16 + l15) * 256 + \
                                      (((ksl * 4 + rg) ^ (l15 & 15)) << 4)); \
        _Pragma("unroll") for (int ni = 0; ni < 8; ++ni) { \
            acc0[ni] = __builtin_amdgcn_mfma_f32_16x16x32_f16(aF0[(KS0) + ksl], bF[ni], acc0[ni], 0, 0, 0); \
            acc1[ni] = __builtin_amdgcn_mfma_f32_16x16x32_f16(aF1[(KS0) + ksl], bF[ni], acc1[ni], 0, 0, 0); \
        } \
    } } while (0)

    f32x4 acc0[8] = {};
    f32x4 acc1[8] = {};
    float rv1[2][4], rv2[2][4];
    int   ri1[2][4];
    #pragma unroll
    for (int mi = 0; mi < 2; ++mi)
        #pragma unroll
        for (int j2 = 0; j2 < 4; ++j2) {
            rv1[mi][j2] = -3.4e38f; rv2[mi][j2] = -3.4e38f; ri1[mi][j2] = 0x7fffffff;
        }

    SCB_STAGE(0, 0, 0);                          // tile0 h0 -> buf0
    VMCNT(0);
    __syncthreads();

    #pragma unroll 1
    for (int t = 0; t < 16; ++t) {
        // phase A: compute h0 from buf0; stage (t,h1) -> buf1
        SCB_STAGE(1, t, 1);
        SC_PHASE(0, 0);
        VMCNT(0);
        __syncthreads();
        // phase B: compute h1 from buf1; stage (t+1,h0) -> buf0; light epilogue
        if (t < 15) SCB_STAGE(0, t + 1, 0);
        SC_PHASE(1, 4);
        {
            const int cb = C0g + t * 128 + l15;
            float esq8[8];
            #pragma unroll
            for (int ni = 0; ni < 8; ++ni) esq8[ni] = esqg[cb + ni * 16];
            #pragma unroll
            for (int mi = 0; mi < 2; ++mi)
                #pragma unroll
                for (int j2 = 0; j2 < 4; ++j2) {
                    float tm = -3.4e38f;
                    #pragma unroll
                    for (int ni = 0; ni < 8; ++ni) {
                        float s = fmaf(2.f, mi ? acc1[ni][j2] : acc0[ni][j2], -esq8[ni]);
                        int c = cb + ni * 16;
                        if (s > rv1[mi][j2]) { rv2[mi][j2] = rv1[mi][j2]; rv1[mi][j2] = s; ri1[mi][j2] = c; }
                        else if (s > rv2[mi][j2]) rv2[mi][j2] = s;
                        tm = fmaxf(tm, s);
                    }
                    // max-only 16-lane reduce (4 shfl + 4 fmax)
                    #pragma unroll
                    for (int m = 1; m < 16; m <<= 1) tm = fmaxf(tm, __shfl_xor(tm, m, 64));
                    if (l15 == 0) {
                        int row = bm + w * 32 + mi * 16 + rg * 4 + j2;
                        tmax[(size_t)(g * 16 + t) * N_TOK + row] = tm;
                    }
                }
            #pragma unroll
            for (int ni = 0; ni < 8; ++ni) {
                acc0[ni] = (f32x4){0.f, 0.f, 0.f, 0.f};
                acc1[ni] = (f32x4){0.f, 0.f, 0.f, 0.f};
            }
        }
        VMCNT(0);
        __syncthreads();
    }

    // ---- final: ONE full (v1,i1,v2) merge per (mi,j2), write cand[g][row] ----
    #pragma unroll
    for (int mi = 0; mi < 2; ++mi)
        #pragma unroll
        for (int j2 = 0; j2 < 4; ++j2) {
            float v1 = rv1[mi][j2], v2 = rv2[mi][j2];
            int i1 = ri1[mi][j2];
            #pragma unroll
            for (int m = 1; m < 16; m <<= 1) {
                float ov1 = __shfl_xor(v1, m, 64);
                int   oi1 = __shfl_xor(i1, m, 64);
                float ov2 = __shfl_xor(v2, m, 64);
                float nv2 = fmaxf(fmaxf(v2, ov2), fminf(v1, ov1));
                if (ov1 > v1 || (ov1 == v1 && oi1 < i1)) { v1 = ov1; i1 = oi1; }
                v2 = nv2;
            }
            if (l15 == 0) {
                int row = bm + w * 32 + mi * 16 + rg * 4 + j2;
                cand[(size_t)g * N_TOK + row] = make_float4(v1, __int_as_float(i1), v2, 0.f);
            }
        }
}

// -------- combine: merge 4 group candidates + measured-norm rescue decision ---
__global__ __launch_bounds__(256) void combine(const float4* __restrict__ cand,
                                               const float2* __restrict__ znorm2,
                                               const float* __restrict__ maxe,
                                               int* __restrict__ idx, float* __restrict__ idxf,
                                               float* __restrict__ rescueT) {
    int row = blockIdx.x * 256 + threadIdx.x;
    float4 p = cand[row];
    float v1 = p.x; int i1 = __float_as_int(p.y); float v2 = p.z;
    #pragma unroll
    for (int g = 1; g < 4; ++g) {
        float4 q = cand[(size_t)g * N_TOK + row];
        float w1 = q.x; int jx = __float_as_int(q.y);
        float nv2 = fmaxf(fmaxf(v2, q.z), fminf(v1, w1));
        if (w1 > v1 || (w1 == v1 && jx < i1)) { v1 = w1; i1 = jx; }
        v2 = nv2;
    }
    float2 zn = znorm2[row];
    float thr = fmaf(2.1f, zn.y * maxe[0] + zn.x * maxe[1], 0.02f);
    idx[row] = i1;
    idxf[row] = (float)i1;
    rescueT[row] = (v1 - v2 <= thr) ? (v1 - thr) : 3.0e38f;
}

// ---- exact rescue: tmax screening; 16 lanes per code (coalesced) f32 rescan ---
__global__ __launch_bounds__(256) void rescue(const float* __restrict__ zf32,
                                              const float* __restrict__ embed,
                                              const float* __restrict__ esq,
                                              const float* __restrict__ tmax,
                                              const float* __restrict__ rescueT,
                                              int* __restrict__ idx, float* __restrict__ idxf) {
    int row = blockIdx.x;
    float t = rescueT[row];
    if (t > 1.0e38f) return;
    __shared__ __align__(16) float zrow[256];
    __shared__ float gv[16];
    __shared__ int   gi[16];
    const int tid = threadIdx.x;
    const int grp = tid >> 4, ln = tid & 15;
    zrow[tid] = zf32[(size_t)row * 256 + tid];
    __syncthreads();
    const float4* zr = (const float4*)zrow;
    float bv = -3.4e38f; int bi = 0x7fffffff;
    for (int nt = 0; nt < 64; ++nt) {
        if (tmax[(size_t)nt * N_TOK + row] < t) continue;  // block-uniform
        #pragma unroll 1
        for (int it = 0; it < 8; ++it) {
            int c = nt * 128 + it * 16 + grp;
            const float4* er = (const float4*)(embed + (size_t)c * 256);
            float d = 0.f;
            #pragma unroll
            for (int q = 0; q < 4; ++q) {
                float4 e4 = er[q * 16 + ln];
                float4 z4 = zr[q * 16 + ln];
                d = fmaf(e4.x, z4.x, d); d = fmaf(e4.y, z4.y, d);
                d = fmaf(e4.z, z4.z, d); d = fmaf(e4.w, z4.w, d);
            }
            #pragma unroll
            for (int m = 1; m < 16; m <<= 1) d += __shfl_xor(d, m, 64);
            if (ln == 0) {
                float s = 2.f * d - esq[c];
                if (s > bv || (s == bv && c < bi)) { bv = s; bi = c; }
            }
        }
    }
    if (ln == 0) { gv[grp] = bv; gi[grp] = bi; }
    __syncthreads();
    if (tid == 0) {
        float v = gv[0]; int i = gi[0];
        #pragma unroll
        for (int k = 1; k < 16; ++k)
            if (gv[k] > v || (gv[k] == v && gi[k] < i)) { v = gv[k]; i = gi[k]; }
        idx[row] = i; idxf[row] = (float)i;
    }
}

// ====== gemm_out: out = embed[idx]@W_out^T + b_out, 4-term, BM=128 BN=128 =====
__global__ __launch_bounds__(256, 2) void gemm_out_mfma(const short* __restrict__ epk,
                                                        const short* __restrict__ wpk,
                                                        const int* __restrict__ idx,
                                                        const float* __restrict__ b_out,
                                                        float* __restrict__ out) {
    __shared__ __align__(16) char smem[65536];
    const int tid = threadIdx.x;
    const int lane = tid & 63, wid = tid >> 6;
    const int wr = wid >> 1, wc = wid & 1;
    const int l15 = lane & 15, rg = lane >> 4;
    const int bm = blockIdx.x << 7, bn = blockIdx.y << 7;
    const int g = tid & 7, rpb = tid >> 3;

    const char* ebp = (const char*)epk;
    const char* wb = (const char*)wpk;
    const int sw = ((g ^ (rpb & 7)) << 4);
    size_t aoff[4], boff[4];
    #pragma unroll
    for (int it = 0; it < 4; ++it) {
        int c = idx[bm + it * 32 + rpb];
        aoff[it] = (size_t)c * 1024 + sw;
        boff[it] = (size_t)(bn + it * 32 + rpb) * 1024 + sw;
    }

    const int ax0 = ((rg ^ (l15 & 7)) << 4);
    const int ax1 = (((rg + 4) ^ (l15 & 7)) << 4);
    const char* aBase = smem + (wr * 64 + l15) * 128;
    const char* bBase = smem + 16384 + (wc * 64 + l15) * 128;

    f32x4 acc[4][4] = {};

#define GOUT_STAGE(BUF, KT) do { \
    size_t aK = (size_t)((((KT) & 3) | (((KT) >> 3) << 2))) * 128; \
    size_t bK = (size_t)((KT) & 7) * 128; \
    char* dA = smem + (BUF) * 32768 + (tid << 4); \
    char* dB = dA + 16384; \
    _Pragma("unroll") for (int it_ = 0; it_ < 4; ++it_) { \
        GLOAD16(ebp + aoff[it_] + aK, dA + it_ * 4096); \
        GLOAD16(wb + boff[it_] + bK, dB + it_ * 4096); } } while (0)

    GOUT_STAGE(0, 0);
    VMCNT(0);
    __syncthreads();
    #pragma unroll 1
    for (int kt = 0; kt < 16; ++kt) {
        const int buf = kt & 1;
        if (kt + 1 < 16) GOUT_STAGE(buf ^ 1, kt + 1);
        const char* aB = aBase + buf * 32768;
        const char* bB = bBase + buf * 32768;
        #pragma unroll
        for (int ks = 0; ks < 2; ++ks) {
            int ax = ks ? ax1 : ax0;
            short8 aF[4], bF[4];
            #pragma unroll
            for (int mi = 0; mi < 4; ++mi) aF[mi] = *(const short8*)(aB + mi * 2048 + ax);
            #pragma unroll
            for (int ni = 0; ni < 4; ++ni) bF[ni] = *(const short8*)(bB + ni * 2048 + ax);
            #pragma unroll
            for (int mi = 0; mi < 4; ++mi)
                #pragma unroll
                for (int ni = 0; ni < 4; ++ni)
                    acc[mi][ni] = __builtin_amdgcn_mfma_f32_16x16x32_bf16(aF[mi], bF[ni], acc[mi][ni], 0, 0, 0);
        }
        VMCNT(0);
        __syncthreads();
    }
    float bb[4];
    #pragma unroll
    for (int ni = 0; ni < 4; ++ni) bb[ni] = b_out[bn + wc * 64 + ni * 16 + l15];
    #pragma unroll
    for (int mi = 0; mi < 4; ++mi)
        #pragma unroll
        for (int ni = 0; ni < 4; ++ni)
            #pragma unroll
            for (int j = 0; j < 4; ++j) {
                int r = bm + wr * 64 + mi * 16 + rg * 4 + j;
                int c = bn + wc * 64 + ni * 16 + l15;
                out[(size_t)r * 512 + c] = acc[mi][ni][j] + bb[ni];
            }
}

// =================== fallback f32 path (ws too small) =========================
__global__ __launch_bounds__(256) void esq_kernel(const float* __restrict__ embed,
                                                  float* __restrict__ esq) {
    int wave = threadIdx.x >> 6, lane = threadIdx.x & 63;
    int c = (blockIdx.x << 2) + wave;
    float4 v = reinterpret_cast<const float4*>(embed + (size_t)c * CBD)[lane];
    float s = v.x * v.x + v.y * v.y + v.z * v.z + v.w * v.w;
    #pragma unroll
    for (int m = 32; m; m >>= 1) s += __shfl_xor(s, m, 64);
    if (!lane) esq[c] = s;
}

template <bool GATHER>
__global__ __launch_bounds__(256) void gemm_nt(const float* __restrict__ A,
                                               const float* __restrict__ B,
                                               const float* __restrict__ bias,
                                               const int* __restrict__ gather,
                                               float* __restrict__ C,
                                               int M, int N, int K) {
    __shared__ __align__(16) float sA[64][68];
    __shared__ __align__(16) float sB[64][68];
    const int tid = threadIdx.x;
    const int tx = tid & 15, ty = tid >> 4;
    const int bm = blockIdx.x << 6, bn = blockIdx.y << 6;
    float acc[4][4] = {};
    for (int k0 = 0; k0 < K; k0 += 64) {
        #pragma unroll
        for (int i = 0; i < 4; ++i) {
            int f = tid + (i << 8);
            int m = f >> 4;
            int k4 = (f & 15) << 2;
            long arow = bm + m;
            if (GATHER) arow = gather[arow];
            float4 v = *reinterpret_cast<const float4*>(A + arow * K + k0 + k4);
            sA[k4 + 0][m] = v.x; sA[k4 + 1][m] = v.y;
            sA[k4 + 2][m] = v.z; sA[k4 + 3][m] = v.w;
            float4 w = *reinterpret_cast<const float4*>(B + (long)(bn + m) * K + k0 + k4);
            sB[k4 + 0][m] = w.x; sB[k4 + 1][m] = w.y;
            sB[k4 + 2][m] = w.z; sB[k4 + 3][m] = w.w;
        }
        __syncthreads();
        #pragma unroll
        for (int kk = 0; kk < 64; ++kk) {
            float4 a = *reinterpret_cast<const float4*>(&sA[kk][ty << 2]);
            float4 b = *reinterpret_cast<const float4*>(&sB[kk][tx << 2]);
            float av[4] = {a.x, a.y, a.z, a.w};
            float bv[4] = {b.x, b.y, b.z, b.w};
            #pragma unroll
            for (int i = 0; i < 4; ++i)
                #pragma unroll
                for (int j = 0; j < 4; ++j)
                    acc[i][j] = fmaf(av[i], bv[j], acc[i][j]);
        }
        __syncthreads();
    }
    #pragma unroll
    for (int i = 0; i < 4; ++i) {
        long m = bm + (ty << 2) + i;
        #pragma unroll
        for (int j = 0; j < 4; ++j) {
            int n = bn + (tx << 2) + j;
            C[m * N + n] = acc[i][j] + bias[n];
        }
    }
}

__global__ __launch_bounds__(256) void score_argmax(const float* __restrict__ z,
                                                    const float* __restrict__ embed,
                                                    const float* __restrict__ esq,
                                                    int* __restrict__ idx_out,
                                                    float* __restrict__ idx_f32) {
    __shared__ __align__(16) float sZ[64][68];
    __shared__ __align__(16) float sE[64][68];
    const int tid = threadIdx.x;
    const int tx = tid & 15, ty = tid >> 4;
    const int bm = blockIdx.x << 6;
    float best[4];
    int bidx[4];
    #pragma unroll
    for (int i = 0; i < 4; ++i) { best[i] = -3.4e38f; bidx[i] = 0; }
    for (int ct = 0; ct < CBS; ct += 64) {
        float acc[4][4] = {};
        for (int k0 = 0; k0 < CBD; k0 += 64) {
            #pragma unroll
            for (int i = 0; i < 4; ++i) {
                int f = tid + (i << 8);
                int m = f >> 4;
                int k4 = (f & 15) << 2;
                float4 v = *reinterpret_cast<const float4*>(z + (long)(bm + m) * CBD + k0 + k4);
                sZ[k4 + 0][m] = v.x; sZ[k4 + 1][m] = v.y;
                sZ[k4 + 2][m] = v.z; sZ[k4 + 3][m] = v.w;
                float4 w = *reinterpret_cast<const float4*>(embed + (long)(ct + m) * CBD + k0 + k4);
                sE[k4 + 0][m] = w.x; sE[k4 + 1][m] = w.y;
                sE[k4 + 2][m] = w.z; sE[k4 + 3][m] = w.w;
            }
            __syncthreads();
            #pragma unroll
            for (int kk = 0; kk < 64; ++kk) {
                float4 a = *reinterpret_cast<const float4*>(&sZ[kk][ty << 2]);
                float4 b = *reinterpret_cast<const float4*>(&sE[kk][tx << 2]);
                float av[4] = {a.x, a.y, a.z, a.w};
                float bv[4] = {b.x, b.y, b.z, b.w};
                #pragma unroll
                for (int i = 0; i < 4; ++i)
                    #pragma unroll
                    for (int j = 0; j < 4; ++j)
                        acc[i][j] = fmaf(av[i], bv[j], acc[i][j]);
            }
            __syncthreads();
        }
        #pragma unroll
        for (int j = 0; j < 4; ++j) {
            int c = ct + (tx << 2) + j;
            float eq = esq[c];
            #pragma unroll
            for (int i = 0; i < 4; ++i) {
                float s = 2.0f * acc[i][j] - eq;
                if (s > best[i] || (s == best[i] && c < bidx[i])) { best[i] = s; bidx[i] = c; }
            }
        }
    }
    #pragma unroll
    for (int i = 0; i < 4; ++i) {
        float b = best[i];
        int bi = bidx[i];
        #pragma unroll
        for (int m = 1; m < 16; m <<= 1) {
            float ob = __shfl_xor(b, m, 64);
            int oi = __shfl_xor(bi, m, 64);
            if (ob > b || (ob == b && oi < bi)) { b = ob; bi = oi; }
        }
        if (tx == 0) {
            int row = bm + (ty << 2) + i;
            idx_out[row] = bi;
            idx_f32[row] = (float)bi;
        }
    }
}

extern "C" void kernel_launch(void* const* d_in, const int* in_sizes, int n_in,
                              void* d_out, int out_size, void* d_ws, size_t ws_size,
                              hipStream_t stream) {
    const float* x     = (const float*)d_in[0];
    const float* embed = (const float*)d_in[1];
    const float* W_in  = (const float*)d_in[2];
    const float* b_in  = (const float*)d_in[3];
    const float* W_out = (const float*)d_in[4];
    const float* b_out = (const float*)d_in[5];

    float* out_idx = (float*)d_out;              // [16384] indices as float
    float* out     = (float*)d_out + N_TOK;      // [16384,512]

    // workspace layout (main path). tmax/cand alias xpack (dead after gemm_in).
    char* ws = (char*)d_ws;
    float*  esq      = (float*)ws;                                   // 32KB
    float*  rescueT  = (float*)(ws + 32768);                         // 64KB
    int*    idx      = (int*)(ws + 98304);                           // 64KB
    float2* znorm2   = (float2*)(ws + 163840);                       // 128KB
    float*  denorm   = (float*)(ws + 294912);                        // 32KB
    float*  maxe     = (float*)(ws + 327680);                        // 256B
    short*  xpack    = (short*)(ws + 327936);                        // 33.55MB
    float*  tmax     = (float*)(ws + 327936);                        // 4MB (alias)
    float4* cand     = (float4*)(ws + 327936 + 4194304);             // 1MB (alias)
    float*  zf32     = (float*)(ws + 327936 + 33554432);             // 16.78MB
    short*  z16      = (short*)((char*)zf32 + 16777216);             // 8.39MB
    short*  e16      = z16 + (size_t)N_TOK * 256;                    // 4.19MB
    short*  epack    = e16 + (size_t)CBS * 256;                      // 8.39MB
    short*  winpk    = epack + (size_t)CBS * 512;                    // 0.52MB
    short*  wopk     = winpk + (size_t)CBD * 1024;                   // 0.52MB
    size_t need = (size_t)((char*)(wopk + (size_t)DIM * 512) - ws);

    if (ws_size >= need) {
        pack_w<9><<<(N_TOK * DIM) / 256, 256, 0, stream>>>(x, xpack);
        pack_w<9><<<(CBD * DIM) / 256, 256, 0, stream>>>(W_in, winpk);
        pack_w<8><<<(DIM * CBD) / 256, 256, 0, stream>>>(W_out, wopk);
        prep_embed<<<CBS / 4, 256, 0, stream>>>(embed, esq, epack, e16, denorm);
        maxe_k<<<1, 256, 0, stream>>>(esq, denorm, maxe);
        // z = x@W_in^T + b_in (4-term MFMA) -> z16 (f16) + zf32 (exact)
        gemm_in_mfma<<<dim3(N_TOK / 64, 2), 256, 0, stream>>>(xpack, winpk, b_in, z16, zf32);
        znorm_k<<<N_TOK / 4, 256, 0, stream>>>(zf32, z16, znorm2);
        // fp16 scores: running top-2 + per-tile max only (light epilogue)
        score_mfma<<<512, 256, 0, stream>>>(z16, e16, esq, tmax, cand);
        // combine 4 group candidates -> idx + measured-norm rescue thresholds
        combine<<<N_TOK / 256, 256, 0, stream>>>(cand, znorm2, maxe, idx, out_idx, rescueT);
        // exact rescue (zf32-based; tmax screening; coalesced scan)
        rescue<<<N_TOK, 256, 0, stream>>>(zf32, embed, esq, tmax, rescueT, idx, out_idx);
        // out = embed[idx]@W_out^T + b_out
        gemm_out_mfma<<<dim3(N_TOK / 128, 4), 256, 0, stream>>>(epack, wopk, idx, b_out, out);
    } else {
        float* z   = (float*)d_ws;
        float* es  = z + (size_t)N_TOK * CBD;
        int*   id  = (int*)(es + CBS);
        gemm_nt<false><<<dim3(N_TOK / 64, CBD / 64), 256, 0, stream>>>(
            x, W_in, b_in, nullptr, z, N_TOK, CBD, DIM);
        esq_kernel<<<CBS / 4, 256, 0, stream>>>(embed, es);
        score_argmax<<<N_TOK / 64, 256, 0, stream>>>(z, embed, es, id, out_idx);
        gemm_nt<true><<<dim3(N_TOK / 64, DIM / 64), 256, 0, stream>>>(
            embed, W_out, b_out, id, out, N_TOK, DIM, CBD);
    }
}

// Round 18
// 234.150 us; speedup vs baseline: 1.1948x; 1.0484x over previous
//
#include <hip/hip_runtime.h>

#define N_TOK 16384   // B*T = 8*2048
#define DIM   512
#define CBD   256     // codebook dim
#define CBS   8192    // codebook size

typedef short short8 __attribute__((ext_vector_type(8)));
typedef float f32x4 __attribute__((ext_vector_type(4)));

#define GLOAD16(g, l) __builtin_amdgcn_global_load_lds( \
    (const __attribute__((address_space(1))) void*)(g), \
    (__attribute__((address_space(3))) void*)(l), 16, 0, 0)

#define VMCNT(n) asm volatile("s_waitcnt vmcnt(" #n ")" ::: "memory")

__device__ inline unsigned short f2bf_rne(float f) {
    unsigned u = __float_as_uint(f);
    unsigned r = (u + 0x7FFFu + ((u >> 16) & 1u)) >> 16;
    return (unsigned short)r;
}
__device__ inline float bf2f(unsigned short h) { return __uint_as_float((unsigned)h << 16); }
__device__ inline short f2h(float f) {
    _Float16 h = (_Float16)f;           // v_cvt_f16_f32, RNE
    short r; __builtin_memcpy(&r, &h, 2); return r;
}
__device__ inline float h2f(short s) {
    _Float16 h; __builtin_memcpy(&h, &s, 2); return (float)h;
}

// ================= packing: 2-term split [hi(K) | lo(K)] per row ==============
template <int LOGK>
__global__ __launch_bounds__(256) void pack_w(const float* __restrict__ src, short* __restrict__ dst) {
    int e = blockIdx.x * 256 + threadIdx.x;
    int r = e >> LOGK, k = e & ((1 << LOGK) - 1);
    float v = src[e];
    unsigned short h = f2bf_rne(v);
    unsigned short l = f2bf_rne(v - bf2f(h));
    size_t base = (size_t)r << (LOGK + 1);
    dst[base + k] = (short)h;
    dst[base + (1 << LOGK) + k] = (short)l;
}

// fused: e_sq + 2-term bf16 pack (gemm_out) + f16 pack (score) + ||e-e16||^2
__global__ __launch_bounds__(256) void prep_embed(const float* __restrict__ embed,
                                                  float* __restrict__ esq,
                                                  short* __restrict__ epack,
                                                  short* __restrict__ e16,
                                                  float* __restrict__ denorm) {
    int wave = threadIdx.x >> 6, lane = threadIdx.x & 63;
    int c = (blockIdx.x << 2) + wave;
    float4 v = reinterpret_cast<const float4*>(embed + (size_t)c * CBD)[lane];
    short4 hs, ls, fs;
    {
        unsigned short h, l;
        h = f2bf_rne(v.x); l = f2bf_rne(v.x - bf2f(h)); hs.x = h; ls.x = l;
        h = f2bf_rne(v.y); l = f2bf_rne(v.y - bf2f(h)); hs.y = h; ls.y = l;
        h = f2bf_rne(v.z); l = f2bf_rne(v.z - bf2f(h)); hs.z = h; ls.z = l;
        h = f2bf_rne(v.w); l = f2bf_rne(v.w - bf2f(h)); hs.w = h; ls.w = l;
    }
    fs.x = f2h(v.x); fs.y = f2h(v.y); fs.z = f2h(v.z); fs.w = f2h(v.w);
    reinterpret_cast<short4*>(epack + (size_t)c * 512)[lane] = hs;
    reinterpret_cast<short4*>(epack + (size_t)c * 512 + 256)[lane] = ls;
    reinterpret_cast<short4*>(e16 + (size_t)c * 256)[lane] = fs;
    float s = v.x * v.x + v.y * v.y + v.z * v.z + v.w * v.w;
    float dx = v.x - h2f(fs.x), dy = v.y - h2f(fs.y);
    float dz = v.z - h2f(fs.z), dw = v.w - h2f(fs.w);
    float ds = dx * dx + dy * dy + dz * dz + dw * dw;
    #pragma unroll
    for (int m = 32; m; m >>= 1) { s += __shfl_xor(s, m, 64); ds += __shfl_xor(ds, m, 64); }
    if (!lane) { esq[c] = s; denorm[c] = ds; }
}

// ---- znorm2[r] = (||z16||, ||zf32 - z16||) ----
__global__ __launch_bounds__(256) void znorm_k(const float* __restrict__ zf32,
                                               const short* __restrict__ z16,
                                               float2* __restrict__ znorm2) {
    int wave = threadIdx.x >> 6, lane = threadIdx.x & 63;
    int r = blockIdx.x * 4 + wave;
    float4 v = reinterpret_cast<const float4*>(zf32 + (size_t)r * 256)[lane];
    short4 h = reinterpret_cast<const short4*>(z16 + (size_t)r * 256)[lane];
    float a = h2f(h.x), b = h2f(h.y), c = h2f(h.z), d = h2f(h.w);
    float s16 = a * a + b * b + c * c + d * d;
    float dx = v.x - a, dy = v.y - b, dz = v.z - c, dw = v.w - d;
    float ds = dx * dx + dy * dy + dz * dz + dw * dw;
    #pragma unroll
    for (int m = 32; m; m >>= 1) { s16 += __shfl_xor(s16, m, 64); ds += __shfl_xor(ds, m, 64); }
    if (!lane) znorm2[r] = make_float2(sqrtf(s16), sqrtf(ds));
}

// ---- maxe[0] = max_c ||e_c||, maxe[1] = max_c ||e_c - e16_c|| ----
__global__ __launch_bounds__(256) void maxe_k(const float* __restrict__ esq,
                                              const float* __restrict__ denorm,
                                              float* __restrict__ maxe) {
    float m = 0.f, md = 0.f;
    #pragma unroll
    for (int k = 0; k < 32; ++k) {
        m = fmaxf(m, esq[threadIdx.x + (k << 8)]);
        md = fmaxf(md, denorm[threadIdx.x + (k << 8)]);
    }
    #pragma unroll
    for (int s = 32; s; s >>= 1) {
        m = fmaxf(m, __shfl_xor(m, s, 64));
        md = fmaxf(md, __shfl_xor(md, s, 64));
    }
    __shared__ float w[4], wd[4];
    if (!(threadIdx.x & 63)) { w[threadIdx.x >> 6] = m; wd[threadIdx.x >> 6] = md; }
    __syncthreads();
    if (threadIdx.x == 0) {
        maxe[0] = sqrtf(fmaxf(fmaxf(w[0], w[1]), fmaxf(w[2], w[3])));
        maxe[1] = sqrtf(fmaxf(fmaxf(wd[0], wd[1]), fmaxf(wd[2], wd[3])));
    }
}

// ============ gemm_in: z = x@W_in^T + b_in, 4-term split-bf16, BM=64 BN=128 ===
__global__ __launch_bounds__(256, 3) void gemm_in_mfma(const short* __restrict__ xpk,
                                                       const short* __restrict__ wpk,
                                                       const float* __restrict__ b_in,
                                                       short* __restrict__ z16,
                                                       float* __restrict__ zf32) {
    __shared__ __align__(16) char smem[49152];
    const int tid = threadIdx.x;
    const int lane = tid & 63, wid = tid >> 6;
    const int l15 = lane & 15, rg = lane >> 4;
    const int bm = blockIdx.x << 6, bn = blockIdx.y << 7;
    const int g = tid & 7, rpb = tid >> 3;

    const char* xb = (const char*)xpk;
    const char* wb = (const char*)wpk;
    const int sw = ((g ^ (rpb & 7)) << 4);
    size_t aoff[2], boff[2][2];
    #pragma unroll
    for (int it = 0; it < 2; ++it)
        aoff[it] = (size_t)(bm + it * 32 + rpb) * 2048 + sw;
    #pragma unroll
    for (int it = 0; it < 4; ++it)
        boff[it >> 1][it & 1] = (size_t)(bn + it * 32 + rpb) * 2048 + sw;

    const int ax0 = ((rg ^ (l15 & 7)) << 4);
    const int ax1 = (((rg + 4) ^ (l15 & 7)) << 4);
    const char* aBase = smem + l15 * 128;
    const char* bBase = smem + 8192 + (wid * 32 + l15) * 128;

    f32x4 acc[4][2] = {};

#define GIN_STAGE(BUF, KT) do { \
    size_t aK = (size_t)(((((KT) >> 4) << 3) | ((KT) & 7))) * 128; \
    size_t bK = (size_t)((((((KT) >> 3) & 1) << 3) | ((KT) & 7))) * 128; \
    char* dA = smem + (BUF) * 24576 + (tid << 4); \
    char* dB = dA + 8192; \
    GLOAD16(xb + aoff[0] + aK, dA); \
    GLOAD16(xb + aoff[1] + aK, dA + 4096); \
    GLOAD16(wb + boff[0][0] + bK, dB); \
    GLOAD16(wb + boff[0][1] + bK, dB + 4096); \
    GLOAD16(wb + boff[1][0] + bK, dB + 8192); \
    GLOAD16(wb + boff[1][1] + bK, dB + 12288); } while (0)

    GIN_STAGE(0, 0);
    VMCNT(0);
    __syncthreads();
    #pragma unroll 1
    for (int kt = 0; kt < 32; ++kt) {
        const int buf = kt & 1;
        if (kt + 1 < 32) GIN_STAGE(buf ^ 1, kt + 1);
        const char* aB = aBase + buf * 24576;
        const char* bB = bBase + buf * 24576;
        #pragma unroll
        for (int ks = 0; ks < 2; ++ks) {
            int ax = ks ? ax1 : ax0;
            short8 aF[4], bF[2];
            #pragma unroll
            for (int mi = 0; mi < 4; ++mi) aF[mi] = *(const short8*)(aB + mi * 2048 + ax);
            #pragma unroll
            for (int ni = 0; ni < 2; ++ni) bF[ni] = *(const short8*)(bB + ni * 2048 + ax);
            #pragma unroll
            for (int mi = 0; mi < 4; ++mi)
                #pragma unroll
                for (int ni = 0; ni < 2; ++ni)
                    acc[mi][ni] = __builtin_amdgcn_mfma_f32_16x16x32_bf16(aF[mi], bF[ni], acc[mi][ni], 0, 0, 0);
        }
        VMCNT(0);
        __syncthreads();
    }
    float bb[2];
    #pragma unroll
    for (int ni = 0; ni < 2; ++ni) bb[ni] = b_in[bn + wid * 32 + ni * 16 + l15];
    #pragma unroll
    for (int mi = 0; mi < 4; ++mi)
        #pragma unroll
        for (int ni = 0; ni < 2; ++ni)
            #pragma unroll
            for (int j = 0; j < 4; ++j) {
                int r = bm + mi * 16 + rg * 4 + j;
                int c = bn + wid * 32 + ni * 16 + l15;
                float s = acc[mi][ni][j] + bb[ni];
                z16[(size_t)r * 256 + c] = f2h(s);
                zf32[(size_t)r * 256 + c] = s;
            }
}

// ===== score: A-in-registers (static idx), half-K B chunks, 2 blocks/CU.
// Running per-lane top-2 across all 16 tiles; per-tile MAX-only breadth-first
// reduce -> tmax[tile][row]; esq tile slice staged into LDS one tile ahead
// (kills per-tile global-latency stall); ONE full merge per block -> cand.
__global__ __launch_bounds__(256, 2) void score_mfma(const short* __restrict__ zpk,
                                                     const short* __restrict__ epk,
                                                     const float* __restrict__ esqg,
                                                     float* __restrict__ tmax,
                                                     float4* __restrict__ cand) {
    __shared__ __align__(16) char smem[67584];   // B: 2x32KB | esq ring 2x1KB @65536
    const int tid = threadIdx.x;
    const int lane = tid & 63, w = tid >> 6;     // 4 waves
    const int l15 = lane & 15, rg = lane >> 4;

    int flat = blockIdx.x;                       // 512 blocks
    int xcd = flat & 7, jb = flat >> 3;          // jb 0..63
    int g  = xcd >> 1;                           // col-group 0..3 (XCD pair)
    int bX = ((xcd & 1) << 6) + jb;              // 0..127 row-block (128 rows)
    const int bm = bX << 7;
    const int C0g = g << 11;                     // g*2048

    // ---- A fragments in registers (once), all indices compile-time ----
    const char* zb = (const char*)zpk;
    short8 aF0[8], aF1[8];
    #pragma unroll
    for (int ks = 0; ks < 8; ++ks) {
        aF0[ks] = *(const short8*)(zb + (size_t)(bm + w * 32 + l15) * 512 + ks * 64 + rg * 16);
        aF1[ks] = *(const short8*)(zb + (size_t)(bm + w * 32 + 16 + l15) * 512 + ks * 64 + rg * 16);
    }

    const char* eb = (const char*)epk;

#define SCB_STAGE(BUF, T, H) do { \
    _Pragma("unroll") for (int i_ = 0; i_ < 8; ++i_) { \
        int u_ = i_ * 256 + tid; \
        int col_ = u_ >> 4, slot_ = u_ & 15; \
        const char* s_ = eb + (size_t)(C0g + (T) * 128 + col_) * 512 + (H) * 256 \
                         + ((slot_ ^ (col_ & 15)) << 4); \
        GLOAD16(s_, smem + (BUF) * 32768 + u_ * 16); \
    } } while (0)

// stage esq slice for tile T into ring slot T&1 (wave 0 only; 1KB, first 512B used)
#define SCE_STAGE(T) do { \
    if (w == 0) { \
        const char* s_ = (const char*)esqg + (size_t)(C0g + (T) * 128) * 4 + lane * 16; \
        GLOAD16(s_, smem + 65536 + (((T) & 1) << 10) + lane * 16); \
    } } while (0)

#define SC_PHASE(BUF, KS0) do { \
    const char* bB = smem + (BUF) * 32768; \
    _Pragma("unroll") for (int ksl = 0; ksl < 4; ++ksl) { \
        short8 bF[8]; \
        _Pragma("unroll") for (int ni = 0; ni < 8; ++ni) \
            bF[ni] = *(const short8*)(bB + (ni * 16 + l15) * 256 + \
                                      (((ksl * 4 + rg) ^ (l15 & 15)) << 4)); \
        _Pragma("unroll") for (int ni = 0; ni < 8; ++ni) { \
            acc0[ni] = __builtin_amdgcn_mfma_f32_16x16x32_f16(aF0[(KS0) + ksl], bF[ni], acc0[ni], 0, 0, 0); \
            acc1[ni] = __builtin_amdgcn_mfma_f32_16x16x32_f16(aF1[(KS0) + ksl], bF[ni], acc1[ni], 0, 0, 0); \
        } \
    } } while (0)

    f32x4 acc0[8] = {};
    f32x4 acc1[8] = {};
    float rv1[2][4], rv2[2][4];
    int   ri1[2][4];
    #pragma unroll
    for (int mi = 0; mi < 2; ++mi)
        #pragma unroll
        for (int j2 = 0; j2 < 4; ++j2) {
            rv1[mi][j2] = -3.4e38f; rv2[mi][j2] = -3.4e38f; ri1[mi][j2] = 0x7fffffff;
        }

    SCB_STAGE(0, 0, 0);                          // tile0 h0 -> buf0
    SCE_STAGE(0);                                // esq tile0 -> slot0
    VMCNT(0);
    __syncthreads();

    #pragma unroll 1
    for (int t = 0; t < 16; ++t) {
        // phase A: compute h0 from buf0; stage (t,h1) -> buf1
        SCB_STAGE(1, t, 1);
        SC_PHASE(0, 0);
        VMCNT(0);
        __syncthreads();
        // phase B: compute h1 from buf1; stage (t+1,h0) -> buf0 + esq(t+1)
        if (t < 15) { SCB_STAGE(0, t + 1, 0); SCE_STAGE(t + 1); }
        SC_PHASE(1, 4);
        {
            const char* eL = smem + 65536 + ((t & 1) << 10);
            float esq8[8];
            #pragma unroll
            for (int ni = 0; ni < 8; ++ni)
                esq8[ni] = *(const float*)(eL + (ni * 16 + l15) * 4);
            float tm[2][4];
            #pragma unroll
            for (int mi = 0; mi < 2; ++mi)
                #pragma unroll
                for (int j2 = 0; j2 < 4; ++j2) {
                    float tmx = -3.4e38f;
                    #pragma unroll
                    for (int ni = 0; ni < 8; ++ni) {
                        float s = fmaf(2.f, mi ? acc1[ni][j2] : acc0[ni][j2], -esq8[ni]);
                        int c = C0g + t * 128 + l15 + ni * 16;
                        if (s > rv1[mi][j2]) { rv2[mi][j2] = rv1[mi][j2]; rv1[mi][j2] = s; ri1[mi][j2] = c; }
                        else if (s > rv2[mi][j2]) rv2[mi][j2] = s;
                        tmx = fmaxf(tmx, s);
                    }
                    tm[mi][j2] = tmx;
                }
            // breadth-first 16-lane max reduce over all 8 values (parallel chains)
            #pragma unroll
            for (int m = 1; m < 16; m <<= 1)
                #pragma unroll
                for (int mi = 0; mi < 2; ++mi)
                    #pragma unroll
                    for (int j2 = 0; j2 < 4; ++j2)
                        tm[mi][j2] = fmaxf(tm[mi][j2], __shfl_xor(tm[mi][j2], m, 64));
            if (l15 == 0) {
                #pragma unroll
                for (int mi = 0; mi < 2; ++mi)
                    #pragma unroll
                    for (int j2 = 0; j2 < 4; ++j2) {
                        int row = bm + w * 32 + mi * 16 + rg * 4 + j2;
                        tmax[(size_t)(g * 16 + t) * N_TOK + row] = tm[mi][j2];
                    }
            }
            #pragma unroll
            for (int ni = 0; ni < 8; ++ni) {
                acc0[ni] = (f32x4){0.f, 0.f, 0.f, 0.f};
                acc1[ni] = (f32x4){0.f, 0.f, 0.f, 0.f};
            }
        }
        VMCNT(0);
        __syncthreads();
    }

    // ---- final: ONE full (v1,i1,v2) merge per (mi,j2), write cand[g][row] ----
    #pragma unroll
    for (int mi = 0; mi < 2; ++mi)
        #pragma unroll
        for (int j2 = 0; j2 < 4; ++j2) {
            float v1 = rv1[mi][j2], v2 = rv2[mi][j2];
            int i1 = ri1[mi][j2];
            #pragma unroll
            for (int m = 1; m < 16; m <<= 1) {
                float ov1 = __shfl_xor(v1, m, 64);
                int   oi1 = __shfl_xor(i1, m, 64);
                float ov2 = __shfl_xor(v2, m, 64);
                float nv2 = fmaxf(fmaxf(v2, ov2), fminf(v1, ov1));
                if (ov1 > v1 || (ov1 == v1 && oi1 < i1)) { v1 = ov1; i1 = oi1; }
                v2 = nv2;
            }
            if (l15 == 0) {
                int row = bm + w * 32 + mi * 16 + rg * 4 + j2;
                cand[(size_t)g * N_TOK + row] = make_float4(v1, __int_as_float(i1), v2, 0.f);
            }
        }
}

// -------- combine: merge 4 group candidates + measured-norm rescue decision ---
__global__ __launch_bounds__(256) void combine(const float4* __restrict__ cand,
                                               const float2* __restrict__ znorm2,
                                               const float* __restrict__ maxe,
                                               int* __restrict__ idx, float* __restrict__ idxf,
                                               float* __restrict__ rescueT) {
    int row = blockIdx.x * 256 + threadIdx.x;
    float4 p = cand[row];
    float v1 = p.x; int i1 = __float_as_int(p.y); float v2 = p.z;
    #pragma unroll
    for (int g = 1; g < 4; ++g) {
        float4 q = cand[(size_t)g * N_TOK + row];
        float w1 = q.x; int jx = __float_as_int(q.y);
        float nv2 = fmaxf(fmaxf(v2, q.z), fminf(v1, w1));
        if (w1 > v1 || (w1 == v1 && jx < i1)) { v1 = w1; i1 = jx; }
        v2 = nv2;
    }
    float2 zn = znorm2[row];
    float thr = fmaf(2.1f, zn.y * maxe[0] + zn.x * maxe[1], 0.02f);
    idx[row] = i1;
    idxf[row] = (float)i1;
    rescueT[row] = (v1 - v2 <= thr) ? (v1 - thr) : 3.0e38f;
}

// ---- exact rescue: tmax screening; 16 lanes per code (coalesced) f32 rescan ---
__global__ __launch_bounds__(256) void rescue(const float* __restrict__ zf32,
                                              const float* __restrict__ embed,
                                              const float* __restrict__ esq,
                                              const float* __restrict__ tmax,
                                              const float* __restrict__ rescueT,
                                              int* __restrict__ idx, float* __restrict__ idxf) {
    int row = blockIdx.x;
    float t = rescueT[row];
    if (t > 1.0e38f) return;
    __shared__ __align__(16) float zrow[256];
    __shared__ float gv[16];
    __shared__ int   gi[16];
    const int tid = threadIdx.x;
    const int grp = tid >> 4, ln = tid & 15;
    zrow[tid] = zf32[(size_t)row * 256 + tid];
    __syncthreads();
    const float4* zr = (const float4*)zrow;
    float bv = -3.4e38f; int bi = 0x7fffffff;
    for (int nt = 0; nt < 64; ++nt) {
        if (tmax[(size_t)nt * N_TOK + row] < t) continue;  // block-uniform
        #pragma unroll 1
        for (int it = 0; it < 8; ++it) {
            int c = nt * 128 + it * 16 + grp;
            const float4* er = (const float4*)(embed + (size_t)c * 256);
            float d = 0.f;
            #pragma unroll
            for (int q = 0; q < 4; ++q) {
                float4 e4 = er[q * 16 + ln];
                float4 z4 = zr[q * 16 + ln];
                d = fmaf(e4.x, z4.x, d); d = fmaf(e4.y, z4.y, d);
                d = fmaf(e4.z, z4.z, d); d = fmaf(e4.w, z4.w, d);
            }
            #pragma unroll
            for (int m = 1; m < 16; m <<= 1) d += __shfl_xor(d, m, 64);
            if (ln == 0) {
                float s = 2.f * d - esq[c];
                if (s > bv || (s == bv && c < bi)) { bv = s; bi = c; }
            }
        }
    }
    if (ln == 0) { gv[grp] = bv; gi[grp] = bi; }
    __syncthreads();
    if (tid == 0) {
        float v = gv[0]; int i = gi[0];
        #pragma unroll
        for (int k = 1; k < 16; ++k)
            if (gv[k] > v || (gv[k] == v && gi[k] < i)) { v = gv[k]; i = gi[k]; }
        idx[row] = i; idxf[row] = (float)i;
    }
}

// ====== gemm_out: out = embed[idx]@W_out^T + b_out, 4-term, BM=128 BN=128 =====
__global__ __launch_bounds__(256, 2) void gemm_out_mfma(const short* __restrict__ epk,
                                                        const short* __restrict__ wpk,
                                                        const int* __restrict__ idx,
                                                        const float* __restrict__ b_out,
                                                        float* __restrict__ out) {
    __shared__ __align__(16) char smem[65536];
    const int tid = threadIdx.x;
    const int lane = tid & 63, wid = tid >> 6;
    const int wr = wid >> 1, wc = wid & 1;
    const int l15 = lane & 15, rg = lane >> 4;
    const int bm = blockIdx.x << 7, bn = blockIdx.y << 7;
    const int g = tid & 7, rpb = tid >> 3;

    const char* ebp = (const char*)epk;
    const char* wb = (const char*)wpk;
    const int sw = ((g ^ (rpb & 7)) << 4);
    size_t aoff[4], boff[4];
    #pragma unroll
    for (int it = 0; it < 4; ++it) {
        int c = idx[bm + it * 32 + rpb];
        aoff[it] = (size_t)c * 1024 + sw;
        boff[it] = (size_t)(bn + it * 32 + rpb) * 1024 + sw;
    }

    const int ax0 = ((rg ^ (l15 & 7)) << 4);
    const int ax1 = (((rg + 4) ^ (l15 & 7)) << 4);
    const char* aBase = smem + (wr * 64 + l15) * 128;
    const char* bBase = smem + 16384 + (wc * 64 + l15) * 128;

    f32x4 acc[4][4] = {};

#define GOUT_STAGE(BUF, KT) do { \
    size_t aK = (size_t)((((KT) & 3) | (((KT) >> 3) << 2))) * 128; \
    size_t bK = (size_t)((KT) & 7) * 128; \
    char* dA = smem + (BUF) * 32768 + (tid << 4); \
    char* dB = dA + 16384; \
    _Pragma("unroll") for (int it_ = 0; it_ < 4; ++it_) { \
        GLOAD16(ebp + aoff[it_] + aK, dA + it_ * 4096); \
        GLOAD16(wb + boff[it_] + bK, dB + it_ * 4096); } } while (0)

    GOUT_STAGE(0, 0);
    VMCNT(0);
    __syncthreads();
    #pragma unroll 1
    for (int kt = 0; kt < 16; ++kt) {
        const int buf = kt & 1;
        if (kt + 1 < 16) GOUT_STAGE(buf ^ 1, kt + 1);
        const char* aB = aBase + buf * 32768;
        const char* bB = bBase + buf * 32768;
        #pragma unroll
        for (int ks = 0; ks < 2; ++ks) {
            int ax = ks ? ax1 : ax0;
            short8 aF[4], bF[4];
            #pragma unroll
            for (int mi = 0; mi < 4; ++mi) aF[mi] = *(const short8*)(aB + mi * 2048 + ax);
            #pragma unroll
            for (int ni = 0; ni < 4; ++ni) bF[ni] = *(const short8*)(bB + ni * 2048 + ax);
            #pragma unroll
            for (int mi = 0; mi < 4; ++mi)
                #pragma unroll
                for (int ni = 0; ni < 4; ++ni)
                    acc[mi][ni] = __builtin_amdgcn_mfma_f32_16x16x32_bf16(aF[mi], bF[ni], acc[mi][ni], 0, 0, 0);
        }
        VMCNT(0);
        __syncthreads();
    }
    float bb[4];
    #pragma unroll
    for (int ni = 0; ni < 4; ++ni) bb[ni] = b_out[bn + wc * 64 + ni * 16 + l15];
    #pragma unroll
    for (int mi = 0; mi < 4; ++mi)
        #pragma unroll
        for (int ni = 0; ni < 4; ++ni)
            #pragma unroll
            for (int j = 0; j < 4; ++j) {
                int r = bm + wr * 64 + mi * 16 + rg * 4 + j;
                int c = bn + wc * 64 + ni * 16 + l15;
                out[(size_t)r * 512 + c] = acc[mi][ni][j] + bb[ni];
            }
}

// =================== fallback f32 path (ws too small) =========================
__global__ __launch_bounds__(256) void esq_kernel(const float* __restrict__ embed,
                                                  float* __restrict__ esq) {
    int wave = threadIdx.x >> 6, lane = threadIdx.x & 63;
    int c = (blockIdx.x << 2) + wave;
    float4 v = reinterpret_cast<const float4*>(embed + (size_t)c * CBD)[lane];
    float s = v.x * v.x + v.y * v.y + v.z * v.z + v.w * v.w;
    #pragma unroll
    for (int m = 32; m; m >>= 1) s += __shfl_xor(s, m, 64);
    if (!lane) esq[c] = s;
}

template <bool GATHER>
__global__ __launch_bounds__(256) void gemm_nt(const float* __restrict__ A,
                                               const float* __restrict__ B,
                                               const float* __restrict__ bias,
                                               const int* __restrict__ gather,
                                               float* __restrict__ C,
                                               int M, int N, int K) {
    __shared__ __align__(16) float sA[64][68];
    __shared__ __align__(16) float sB[64][68];
    const int tid = threadIdx.x;
    const int tx = tid & 15, ty = tid >> 4;
    const int bm = blockIdx.x << 6, bn = blockIdx.y << 6;
    float acc[4][4] = {};
    for (int k0 = 0; k0 < K; k0 += 64) {
        #pragma unroll
        for (int i = 0; i < 4; ++i) {
            int f = tid + (i << 8);
            int m = f >> 4;
            int k4 = (f & 15) << 2;
            long arow = bm + m;
            if (GATHER) arow = gather[arow];
            float4 v = *reinterpret_cast<const float4*>(A + arow * K + k0 + k4);
            sA[k4 + 0][m] = v.x; sA[k4 + 1][m] = v.y;
            sA[k4 + 2][m] = v.z; sA[k4 + 3][m] = v.w;
            float4 w = *reinterpret_cast<const float4*>(B + (long)(bn + m) * K + k0 + k4);
            sB[k4 + 0][m] = w.x; sB[k4 + 1][m] = w.y;
            sB[k4 + 2][m] = w.z; sB[k4 + 3][m] = w.w;
        }
        __syncthreads();
        #pragma unroll
        for (int kk = 0; kk < 64; ++kk) {
            float4 a = *reinterpret_cast<const float4*>(&sA[kk][ty << 2]);
            float4 b = *reinterpret_cast<const float4*>(&sB[kk][tx << 2]);
            float av[4] = {a.x, a.y, a.z, a.w};
            float bv[4] = {b.x, b.y, b.z, b.w};
            #pragma unroll
            for (int i = 0; i < 4; ++i)
                #pragma unroll
                for (int j = 0; j < 4; ++j)
                    acc[i][j] = fmaf(av[i], bv[j], acc[i][j]);
        }
        __syncthreads();
    }
    #pragma unroll
    for (int i = 0; i < 4; ++i) {
        long m = bm + (ty << 2) + i;
        #pragma unroll
        for (int j = 0; j < 4; ++j) {
            int n = bn + (tx << 2) + j;
            C[m * N + n] = acc[i][j] + bias[n];
        }
    }
}

__global__ __launch_bounds__(256) void score_argmax(const float* __restrict__ z,
                                                    const float* __restrict__ embed,
                                                    const float* __restrict__ esq,
                                                    int* __restrict__ idx_out,
                                                    float* __restrict__ idx_f32) {
    __shared__ __align__(16) float sZ[64][68];
    __shared__ __align__(16) float sE[64][68];
    const int tid = threadIdx.x;
    const int tx = tid & 15, ty = tid >> 4;
    const int bm = blockIdx.x << 6;
    float best[4];
    int bidx[4];
    #pragma unroll
    for (int i = 0; i < 4; ++i) { best[i] = -3.4e38f; bidx[i] = 0; }
    for (int ct = 0; ct < CBS; ct += 64) {
        float acc[4][4] = {};
        for (int k0 = 0; k0 < CBD; k0 += 64) {
            #pragma unroll
            for (int i = 0; i < 4; ++i) {
                int f = tid + (i << 8);
                int m = f >> 4;
                int k4 = (f & 15) << 2;
                float4 v = *reinterpret_cast<const float4*>(z + (long)(bm + m) * CBD + k0 + k4);
                sZ[k4 + 0][m] = v.x; sZ[k4 + 1][m] = v.y;
                sZ[k4 + 2][m] = v.z; sZ[k4 + 3][m] = v.w;
                float4 w = *reinterpret_cast<const float4*>(embed + (long)(ct + m) * CBD + k0 + k4);
                sE[k4 + 0][m] = w.x; sE[k4 + 1][m] = w.y;
                sE[k4 + 2][m] = w.z; sE[k4 + 3][m] = w.w;
            }
            __syncthreads();
            #pragma unroll
            for (int kk = 0; kk < 64; ++kk) {
                float4 a = *reinterpret_cast<const float4*>(&sZ[kk][ty << 2]);
                float4 b = *reinterpret_cast<const float4*>(&sE[kk][tx << 2]);
                float av[4] = {a.x, a.y, a.z, a.w};
                float bv[4] = {b.x, b.y, b.z, b.w};
                #pragma unroll
                for (int i = 0; i < 4; ++i)
                    #pragma unroll
                    for (int j = 0; j < 4; ++j)
                        acc[i][j] = fmaf(av[i], bv[j], acc[i][j]);
            }
            __syncthreads();
        }
        #pragma unroll
        for (int j = 0; j < 4; ++j) {
            int c = ct + (tx << 2) + j;
            float eq = esq[c];
            #pragma unroll
            for (int i = 0; i < 4; ++i) {
                float s = 2.0f * acc[i][j] - eq;
                if (s > best[i] || (s == best[i] && c < bidx[i])) { best[i] = s; bidx[i] = c; }
            }
        }
    }
    #pragma unroll
    for (int i = 0; i < 4; ++i) {
        float b = best[i];
        int bi = bidx[i];
        #pragma unroll
        for (int m = 1; m < 16; m <<= 1) {
            float ob = __shfl_xor(b, m, 64);
            int oi = __shfl_xor(bi, m, 64);
            if (ob > b || (ob == b && oi < bi)) { b = ob; bi = oi; }
        }
        if (tx == 0) {
            int row = bm + (ty << 2) + i;
            idx_out[row] = bi;
            idx_f32[row] = (float)bi;
        }
    }
}

extern "C" void kernel_launch(void* const* d_in, const int* in_sizes, int n_in,
                              void* d_out, int out_size, void* d_ws, size_t ws_size,
                              hipStream_t stream) {
    const float* x     = (const float*)d_in[0];
    const float* embed = (const float*)d_in[1];
    const float* W_in  = (const float*)d_in[2];
    const float* b_in  = (const float*)d_in[3];
    const float* W_out = (const float*)d_in[4];
    const float* b_out = (const float*)d_in[5];

    float* out_idx = (float*)d_out;              // [16384] indices as float
    float* out     = (float*)d_out + N_TOK;      // [16384,512]

    // workspace layout (main path). tmax/cand alias xpack (dead after gemm_in).
    char* ws = (char*)d_ws;
    float*  esq      = (float*)ws;                                   // 32KB
    float*  rescueT  = (float*)(ws + 32768);                         // 64KB
    int*    idx      = (int*)(ws + 98304);                           // 64KB
    float2* znorm2   = (float2*)(ws + 163840);                       // 128KB
    float*  denorm   = (float*)(ws + 294912);                        // 32KB
    float*  maxe     = (float*)(ws + 327680);                        // 256B
    short*  xpack    = (short*)(ws + 327936);                        // 33.55MB
    float*  tmax     = (float*)(ws + 327936);                        // 4MB (alias)
    float4* cand     = (float4*)(ws + 327936 + 4194304);             // 1MB (alias)
    float*  zf32     = (float*)(ws + 327936 + 33554432);             // 16.78MB
    short*  z16      = (short*)((char*)zf32 + 16777216);             // 8.39MB
    short*  e16      = z16 + (size_t)N_TOK * 256;                    // 4.19MB
    short*  epack    = e16 + (size_t)CBS * 256;                      // 8.39MB
    short*  winpk    = epack + (size_t)CBS * 512;                    // 0.52MB
    short*  wopk     = winpk + (size_t)CBD * 1024;                   // 0.52MB
    size_t need = (size_t)((char*)(wopk + (size_t)DIM * 512) - ws);

    if (ws_size >= need) {
        pack_w<9><<<(N_TOK * DIM) / 256, 256, 0, stream>>>(x, xpack);
        pack_w<9><<<(CBD * DIM) / 256, 256, 0, stream>>>(W_in, winpk);
        pack_w<8><<<(DIM * CBD) / 256, 256, 0, stream>>>(W_out, wopk);
        prep_embed<<<CBS / 4, 256, 0, stream>>>(embed, esq, epack, e16, denorm);
        maxe_k<<<1, 256, 0, stream>>>(esq, denorm, maxe);
        // z = x@W_in^T + b_in (4-term MFMA) -> z16 (f16) + zf32 (exact)
        gemm_in_mfma<<<dim3(N_TOK / 64, 2), 256, 0, stream>>>(xpack, winpk, b_in, z16, zf32);
        znorm_k<<<N_TOK / 4, 256, 0, stream>>>(zf32, z16, znorm2);
        // fp16 scores: running top-2 + LDS-staged esq + breadth-first tile max
        score_mfma<<<512, 256, 0, stream>>>(z16, e16, esq, tmax, cand);
        // combine 4 group candidates -> idx + measured-norm rescue thresholds
        combine<<<N_TOK / 256, 256, 0, stream>>>(cand, znorm2, maxe, idx, out_idx, rescueT);
        // exact rescue (zf32-based; tmax screening; coalesced scan)
        rescue<<<N_TOK, 256, 0, stream>>>(zf32, embed, esq, tmax, rescueT, idx, out_idx);
        // out = embed[idx]@W_out^T + b_out
        gemm_out_mfma<<<dim3(N_TOK / 128, 4), 256, 0, stream>>>(epack, wopk, idx, b_out, out);
    } else {
        float* z   = (float*)d_ws;
        float* es  = z + (size_t)N_TOK * CBD;
        int*   id  = (int*)(es + CBS);
        gemm_nt<false><<<dim3(N_TOK / 64, CBD / 64), 256, 0, stream>>>(
            x, W_in, b_in, nullptr, z, N_TOK, CBD, DIM);
        esq_kernel<<<CBS / 4, 256, 0, stream>>>(embed, es);
        score_argmax<<<N_TOK / 64, 256, 0, stream>>>(z, embed, es, id, out_idx);
        gemm_nt<true><<<dim3(N_TOK / 64, DIM / 64), 256, 0, stream>>>(
            embed, W_out, b_out, id, out, N_TOK, DIM, CBD);
    }
}

// Round 19
// 227.773 us; speedup vs baseline: 1.2283x; 1.0280x over previous
//
#include <hip/hip_runtime.h>

#define N_TOK 16384   // B*T = 8*2048
#define DIM   512
#define CBD   256     // codebook dim
#define CBS   8192    // codebook size

typedef short short8 __attribute__((ext_vector_type(8)));
typedef float f32x4 __attribute__((ext_vector_type(4)));

#define GLOAD16(g, l) __builtin_amdgcn_global_load_lds( \
    (const __attribute__((address_space(1))) void*)(g), \
    (__attribute__((address_space(3))) void*)(l), 16, 0, 0)

#define VMCNT(n) asm volatile("s_waitcnt vmcnt(" #n ")" ::: "memory")

__device__ inline unsigned short f2bf_rne(float f) {
    unsigned u = __float_as_uint(f);
    unsigned r = (u + 0x7FFFu + ((u >> 16) & 1u)) >> 16;
    return (unsigned short)r;
}
__device__ inline float bf2f(unsigned short h) { return __uint_as_float((unsigned)h << 16); }
__device__ inline short f2h(float f) {
    _Float16 h = (_Float16)f;           // v_cvt_f16_f32, RNE
    short r; __builtin_memcpy(&r, &h, 2); return r;
}
__device__ inline float h2f(short s) {
    _Float16 h; __builtin_memcpy(&h, &s, 2); return (float)h;
}

// ================= packing: 2-term split [hi(K) | lo(K)] per row ==============
template <int LOGK>
__global__ __launch_bounds__(256) void pack_w(const float* __restrict__ src, short* __restrict__ dst) {
    int e = blockIdx.x * 256 + threadIdx.x;
    int r = e >> LOGK, k = e & ((1 << LOGK) - 1);
    float v = src[e];
    unsigned short h = f2bf_rne(v);
    unsigned short l = f2bf_rne(v - bf2f(h));
    size_t base = (size_t)r << (LOGK + 1);
    dst[base + k] = (short)h;
    dst[base + (1 << LOGK) + k] = (short)l;
}

// ---- 1-term fp16 pack (for W_out) ----
__global__ __launch_bounds__(256) void pack_h(const float* __restrict__ src, short* __restrict__ dst) {
    int e = blockIdx.x * 256 + threadIdx.x;
    dst[e] = f2h(src[e]);
}

// fused: e_sq + f16 pack (score + gemm_out A) + ||e-e16||^2
__global__ __launch_bounds__(256) void prep_embed(const float* __restrict__ embed,
                                                  float* __restrict__ esq,
                                                  short* __restrict__ e16,
                                                  float* __restrict__ denorm) {
    int wave = threadIdx.x >> 6, lane = threadIdx.x & 63;
    int c = (blockIdx.x << 2) + wave;
    float4 v = reinterpret_cast<const float4*>(embed + (size_t)c * CBD)[lane];
    short4 fs;
    fs.x = f2h(v.x); fs.y = f2h(v.y); fs.z = f2h(v.z); fs.w = f2h(v.w);
    reinterpret_cast<short4*>(e16 + (size_t)c * 256)[lane] = fs;
    float s = v.x * v.x + v.y * v.y + v.z * v.z + v.w * v.w;
    float dx = v.x - h2f(fs.x), dy = v.y - h2f(fs.y);
    float dz = v.z - h2f(fs.z), dw = v.w - h2f(fs.w);
    float ds = dx * dx + dy * dy + dz * dz + dw * dw;
    #pragma unroll
    for (int m = 32; m; m >>= 1) { s += __shfl_xor(s, m, 64); ds += __shfl_xor(ds, m, 64); }
    if (!lane) { esq[c] = s; denorm[c] = ds; }
}

// ---- znorm2[r] = (||z16||, ||zf32 - z16||) ----
__global__ __launch_bounds__(256) void znorm_k(const float* __restrict__ zf32,
                                               const short* __restrict__ z16,
                                               float2* __restrict__ znorm2) {
    int wave = threadIdx.x >> 6, lane = threadIdx.x & 63;
    int r = blockIdx.x * 4 + wave;
    float4 v = reinterpret_cast<const float4*>(zf32 + (size_t)r * 256)[lane];
    short4 h = reinterpret_cast<const short4*>(z16 + (size_t)r * 256)[lane];
    float a = h2f(h.x), b = h2f(h.y), c = h2f(h.z), d = h2f(h.w);
    float s16 = a * a + b * b + c * c + d * d;
    float dx = v.x - a, dy = v.y - b, dz = v.z - c, dw = v.w - d;
    float ds = dx * dx + dy * dy + dz * dz + dw * dw;
    #pragma unroll
    for (int m = 32; m; m >>= 1) { s16 += __shfl_xor(s16, m, 64); ds += __shfl_xor(ds, m, 64); }
    if (!lane) znorm2[r] = make_float2(sqrtf(s16), sqrtf(ds));
}

// ---- maxe[0] = max_c ||e_c||, maxe[1] = max_c ||e_c - e16_c|| ----
__global__ __launch_bounds__(256) void maxe_k(const float* __restrict__ esq,
                                              const float* __restrict__ denorm,
                                              float* __restrict__ maxe) {
    float m = 0.f, md = 0.f;
    #pragma unroll
    for (int k = 0; k < 32; ++k) {
        m = fmaxf(m, esq[threadIdx.x + (k << 8)]);
        md = fmaxf(md, denorm[threadIdx.x + (k << 8)]);
    }
    #pragma unroll
    for (int s = 32; s; s >>= 1) {
        m = fmaxf(m, __shfl_xor(m, s, 64));
        md = fmaxf(md, __shfl_xor(md, s, 64));
    }
    __shared__ float w[4], wd[4];
    if (!(threadIdx.x & 63)) { w[threadIdx.x >> 6] = m; wd[threadIdx.x >> 6] = md; }
    __syncthreads();
    if (threadIdx.x == 0) {
        maxe[0] = sqrtf(fmaxf(fmaxf(w[0], w[1]), fmaxf(w[2], w[3])));
        maxe[1] = sqrtf(fmaxf(fmaxf(wd[0], wd[1]), fmaxf(wd[2], wd[3])));
    }
}

// ============ gemm_in: z = x@W_in^T + b_in, 4-term split-bf16, BM=64 BN=128 ===
__global__ __launch_bounds__(256, 3) void gemm_in_mfma(const short* __restrict__ xpk,
                                                       const short* __restrict__ wpk,
                                                       const float* __restrict__ b_in,
                                                       short* __restrict__ z16,
                                                       float* __restrict__ zf32) {
    __shared__ __align__(16) char smem[49152];
    const int tid = threadIdx.x;
    const int lane = tid & 63, wid = tid >> 6;
    const int l15 = lane & 15, rg = lane >> 4;
    const int bm = blockIdx.x << 6, bn = blockIdx.y << 7;
    const int g = tid & 7, rpb = tid >> 3;

    const char* xb = (const char*)xpk;
    const char* wb = (const char*)wpk;
    const int sw = ((g ^ (rpb & 7)) << 4);
    size_t aoff[2], boff[2][2];
    #pragma unroll
    for (int it = 0; it < 2; ++it)
        aoff[it] = (size_t)(bm + it * 32 + rpb) * 2048 + sw;
    #pragma unroll
    for (int it = 0; it < 4; ++it)
        boff[it >> 1][it & 1] = (size_t)(bn + it * 32 + rpb) * 2048 + sw;

    const int ax0 = ((rg ^ (l15 & 7)) << 4);
    const int ax1 = (((rg + 4) ^ (l15 & 7)) << 4);
    const char* aBase = smem + l15 * 128;
    const char* bBase = smem + 8192 + (wid * 32 + l15) * 128;

    f32x4 acc[4][2] = {};

#define GIN_STAGE(BUF, KT) do { \
    size_t aK = (size_t)(((((KT) >> 4) << 3) | ((KT) & 7))) * 128; \
    size_t bK = (size_t)((((((KT) >> 3) & 1) << 3) | ((KT) & 7))) * 128; \
    char* dA = smem + (BUF) * 24576 + (tid << 4); \
    char* dB = dA + 8192; \
    GLOAD16(xb + aoff[0] + aK, dA); \
    GLOAD16(xb + aoff[1] + aK, dA + 4096); \
    GLOAD16(wb + boff[0][0] + bK, dB); \
    GLOAD16(wb + boff[0][1] + bK, dB + 4096); \
    GLOAD16(wb + boff[1][0] + bK, dB + 8192); \
    GLOAD16(wb + boff[1][1] + bK, dB + 12288); } while (0)

    GIN_STAGE(0, 0);
    VMCNT(0);
    __syncthreads();
    #pragma unroll 1
    for (int kt = 0; kt < 32; ++kt) {
        const int buf = kt & 1;
        if (kt + 1 < 32) GIN_STAGE(buf ^ 1, kt + 1);
        const char* aB = aBase + buf * 24576;
        const char* bB = bBase + buf * 24576;
        #pragma unroll
        for (int ks = 0; ks < 2; ++ks) {
            int ax = ks ? ax1 : ax0;
            short8 aF[4], bF[2];
            #pragma unroll
            for (int mi = 0; mi < 4; ++mi) aF[mi] = *(const short8*)(aB + mi * 2048 + ax);
            #pragma unroll
            for (int ni = 0; ni < 2; ++ni) bF[ni] = *(const short8*)(bB + ni * 2048 + ax);
            #pragma unroll
            for (int mi = 0; mi < 4; ++mi)
                #pragma unroll
                for (int ni = 0; ni < 2; ++ni)
                    acc[mi][ni] = __builtin_amdgcn_mfma_f32_16x16x32_bf16(aF[mi], bF[ni], acc[mi][ni], 0, 0, 0);
        }
        VMCNT(0);
        __syncthreads();
    }
    float bb[2];
    #pragma unroll
    for (int ni = 0; ni < 2; ++ni) bb[ni] = b_in[bn + wid * 32 + ni * 16 + l15];
    #pragma unroll
    for (int mi = 0; mi < 4; ++mi)
        #pragma unroll
        for (int ni = 0; ni < 2; ++ni)
            #pragma unroll
            for (int j = 0; j < 4; ++j) {
                int r = bm + mi * 16 + rg * 4 + j;
                int c = bn + wid * 32 + ni * 16 + l15;
                float s = acc[mi][ni][j] + bb[ni];
                z16[(size_t)r * 256 + c] = f2h(s);
                zf32[(size_t)r * 256 + c] = s;
            }
}

// ===== score: A-in-registers (static idx), half-K B chunks, 2 blocks/CU.
// Running per-lane top-2; per-tile MAX breadth-first -> tmax; esq in LDS ring;
// ONE full merge per block -> cand.
__global__ __launch_bounds__(256, 2) void score_mfma(const short* __restrict__ zpk,
                                                     const short* __restrict__ epk,
                                                     const float* __restrict__ esqg,
                                                     float* __restrict__ tmax,
                                                     float4* __restrict__ cand) {
    __shared__ __align__(16) char smem[67584];   // B: 2x32KB | esq ring 2x1KB @65536
    const int tid = threadIdx.x;
    const int lane = tid & 63, w = tid >> 6;     // 4 waves
    const int l15 = lane & 15, rg = lane >> 4;

    int flat = blockIdx.x;                       // 512 blocks
    int xcd = flat & 7, jb = flat >> 3;          // jb 0..63
    int g  = xcd >> 1;                           // col-group 0..3 (XCD pair)
    int bX = ((xcd & 1) << 6) + jb;              // 0..127 row-block (128 rows)
    const int bm = bX << 7;
    const int C0g = g << 11;                     // g*2048

    const char* zb = (const char*)zpk;
    short8 aF0[8], aF1[8];
    #pragma unroll
    for (int ks = 0; ks < 8; ++ks) {
        aF0[ks] = *(const short8*)(zb + (size_t)(bm + w * 32 + l15) * 512 + ks * 64 + rg * 16);
        aF1[ks] = *(const short8*)(zb + (size_t)(bm + w * 32 + 16 + l15) * 512 + ks * 64 + rg * 16);
    }

    const char* eb = (const char*)epk;

#define SCB_STAGE(BUF, T, H) do { \
    _Pragma("unroll") for (int i_ = 0; i_ < 8; ++i_) { \
        int u_ = i_ * 256 + tid; \
        int col_ = u_ >> 4, slot_ = u_ & 15; \
        const char* s_ = eb + (size_t)(C0g + (T) * 128 + col_) * 512 + (H) * 256 \
                         + ((slot_ ^ (col_ & 15)) << 4); \
        GLOAD16(s_, smem + (BUF) * 32768 + u_ * 16); \
    } } while (0)

#define SCE_STAGE(T) do { \
    if (w == 0) { \
        const char* s_ = (const char*)esqg + (size_t)(C0g + (T) * 128) * 4 + lane * 16; \
        GLOAD16(s_, smem + 65536 + (((T) & 1) << 10) + lane * 16); \
    } } while (0)

#define SC_PHASE(BUF, KS0) do { \
    const char* bB = smem + (BUF) * 32768; \
    _Pragma("unroll") for (int ksl = 0; ksl < 4; ++ksl) { \
        short8 bF[8]; \
        _Pragma("unroll") for (int ni = 0; ni < 8; ++ni) \
            bF[ni] = *(const short8*)(bB + (ni * 16 + l15) * 256 + \
                                      (((ksl * 4 + rg) ^ (l15 & 15)) << 4)); \
        _Pragma("unroll") for (int ni = 0; ni < 8; ++ni) { \
            acc0[ni] = __builtin_amdgcn_mfma_f32_16x16x32_f16(aF0[(KS0) + ksl], bF[ni], acc0[ni], 0, 0, 0); \
            acc1[ni] = __builtin_amdgcn_mfma_f32_16x16x32_f16(aF1[(KS0) + ksl], bF[ni], acc1[ni], 0, 0, 0); \
        } \
    } } while (0)

    f32x4 acc0[8] = {};
    f32x4 acc1[8] = {};
    float rv1[2][4], rv2[2][4];
    int   ri1[2][4];
    #pragma unroll
    for (int mi = 0; mi < 2; ++mi)
        #pragma unroll
        for (int j2 = 0; j2 < 4; ++j2) {
            rv1[mi][j2] = -3.4e38f; rv2[mi][j2] = -3.4e38f; ri1[mi][j2] = 0x7fffffff;
        }

    SCB_STAGE(0, 0, 0);
    SCE_STAGE(0);
    VMCNT(0);
    __syncthreads();

    #pragma unroll 1
    for (int t = 0; t < 16; ++t) {
        SCB_STAGE(1, t, 1);
        SC_PHASE(0, 0);
        VMCNT(0);
        __syncthreads();
        if (t < 15) { SCB_STAGE(0, t + 1, 0); SCE_STAGE(t + 1); }
        SC_PHASE(1, 4);
        {
            const char* eL = smem + 65536 + ((t & 1) << 10);
            float esq8[8];
            #pragma unroll
            for (int ni = 0; ni < 8; ++ni)
                esq8[ni] = *(const float*)(eL + (ni * 16 + l15) * 4);
            float tm[2][4];
            #pragma unroll
            for (int mi = 0; mi < 2; ++mi)
                #pragma unroll
                for (int j2 = 0; j2 < 4; ++j2) {
                    float tmx = -3.4e38f;
                    #pragma unroll
                    for (int ni = 0; ni < 8; ++ni) {
                        float s = fmaf(2.f, mi ? acc1[ni][j2] : acc0[ni][j2], -esq8[ni]);
                        int c = C0g + t * 128 + l15 + ni * 16;
                        if (s > rv1[mi][j2]) { rv2[mi][j2] = rv1[mi][j2]; rv1[mi][j2] = s; ri1[mi][j2] = c; }
                        else if (s > rv2[mi][j2]) rv2[mi][j2] = s;
                        tmx = fmaxf(tmx, s);
                    }
                    tm[mi][j2] = tmx;
                }
            #pragma unroll
            for (int m = 1; m < 16; m <<= 1)
                #pragma unroll
                for (int mi = 0; mi < 2; ++mi)
                    #pragma unroll
                    for (int j2 = 0; j2 < 4; ++j2)
                        tm[mi][j2] = fmaxf(tm[mi][j2], __shfl_xor(tm[mi][j2], m, 64));
            if (l15 == 0) {
                #pragma unroll
                for (int mi = 0; mi < 2; ++mi)
                    #pragma unroll
                    for (int j2 = 0; j2 < 4; ++j2) {
                        int row = bm + w * 32 + mi * 16 + rg * 4 + j2;
                        tmax[(size_t)(g * 16 + t) * N_TOK + row] = tm[mi][j2];
                    }
            }
            #pragma unroll
            for (int ni = 0; ni < 8; ++ni) {
                acc0[ni] = (f32x4){0.f, 0.f, 0.f, 0.f};
                acc1[ni] = (f32x4){0.f, 0.f, 0.f, 0.f};
            }
        }
        VMCNT(0);
        __syncthreads();
    }

    #pragma unroll
    for (int mi = 0; mi < 2; ++mi)
        #pragma unroll
        for (int j2 = 0; j2 < 4; ++j2) {
            float v1 = rv1[mi][j2], v2 = rv2[mi][j2];
            int i1 = ri1[mi][j2];
            #pragma unroll
            for (int m = 1; m < 16; m <<= 1) {
                float ov1 = __shfl_xor(v1, m, 64);
                int   oi1 = __shfl_xor(i1, m, 64);
                float ov2 = __shfl_xor(v2, m, 64);
                float nv2 = fmaxf(fmaxf(v2, ov2), fminf(v1, ov1));
                if (ov1 > v1 || (ov1 == v1 && oi1 < i1)) { v1 = ov1; i1 = oi1; }
                v2 = nv2;
            }
            if (l15 == 0) {
                int row = bm + w * 32 + mi * 16 + rg * 4 + j2;
                cand[(size_t)g * N_TOK + row] = make_float4(v1, __int_as_float(i1), v2, 0.f);
            }
        }
}

// -------- combine: merge 4 group candidates + measured-norm rescue decision ---
__global__ __launch_bounds__(256) void combine(const float4* __restrict__ cand,
                                               const float2* __restrict__ znorm2,
                                               const float* __restrict__ maxe,
                                               int* __restrict__ idx, float* __restrict__ idxf,
                                               float* __restrict__ rescueT) {
    int row = blockIdx.x * 256 + threadIdx.x;
    float4 p = cand[row];
    float v1 = p.x; int i1 = __float_as_int(p.y); float v2 = p.z;
    #pragma unroll
    for (int g = 1; g < 4; ++g) {
        float4 q = cand[(size_t)g * N_TOK + row];
        float w1 = q.x; int jx = __float_as_int(q.y);
        float nv2 = fmaxf(fmaxf(v2, q.z), fminf(v1, w1));
        if (w1 > v1 || (w1 == v1 && jx < i1)) { v1 = w1; i1 = jx; }
        v2 = nv2;
    }
    float2 zn = znorm2[row];
    float thr = fmaf(2.1f, zn.y * maxe[0] + zn.x * maxe[1], 0.02f);
    idx[row] = i1;
    idxf[row] = (float)i1;
    rescueT[row] = (v1 - v2 <= thr) ? (v1 - thr) : 3.0e38f;
}

// ---- exact rescue: tmax screening; 16 lanes per code (coalesced) f32 rescan ---
__global__ __launch_bounds__(256) void rescue(const float* __restrict__ zf32,
                                              const float* __restrict__ embed,
                                              const float* __restrict__ esq,
                                              const float* __restrict__ tmax,
                                              const float* __restrict__ rescueT,
                                              int* __restrict__ idx, float* __restrict__ idxf) {
    int row = blockIdx.x;
    float t = rescueT[row];
    if (t > 1.0e38f) return;
    __shared__ __align__(16) float zrow[256];
    __shared__ float gv[16];
    __shared__ int   gi[16];
    const int tid = threadIdx.x;
    const int grp = tid >> 4, ln = tid & 15;
    zrow[tid] = zf32[(size_t)row * 256 + tid];
    __syncthreads();
    const float4* zr = (const float4*)zrow;
    float bv = -3.4e38f; int bi = 0x7fffffff;
    for (int nt = 0; nt < 64; ++nt) {
        if (tmax[(size_t)nt * N_TOK + row] < t) continue;  // block-uniform
        #pragma unroll 1
        for (int it = 0; it < 8; ++it) {
            int c = nt * 128 + it * 16 + grp;
            const float4* er = (const float4*)(embed + (size_t)c * 256);
            float d = 0.f;
            #pragma unroll
            for (int q = 0; q < 4; ++q) {
                float4 e4 = er[q * 16 + ln];
                float4 z4 = zr[q * 16 + ln];
                d = fmaf(e4.x, z4.x, d); d = fmaf(e4.y, z4.y, d);
                d = fmaf(e4.z, z4.z, d); d = fmaf(e4.w, z4.w, d);
            }
            #pragma unroll
            for (int m = 1; m < 16; m <<= 1) d += __shfl_xor(d, m, 64);
            if (ln == 0) {
                float s = 2.f * d - esq[c];
                if (s > bv || (s == bv && c < bi)) { bv = s; bi = c; }
            }
        }
    }
    if (ln == 0) { gv[grp] = bv; gi[grp] = bi; }
    __syncthreads();
    if (tid == 0) {
        float v = gv[0]; int i = gi[0];
        #pragma unroll
        for (int k = 1; k < 16; ++k)
            if (gv[k] > v || (gv[k] == v && gi[k] < i)) { v = gv[k]; i = gi[k]; }
        idx[row] = i; idxf[row] = (float)i;
    }
}

// ====== gemm_out16: out = e16[idx]@wout16^T + b_out, 1-term fp16, BM=128 BN=128
// K=256 f16 (512B rows), 4 chunks of 128B, double-buffered 64KB -> 2 blocks/CU.
__global__ __launch_bounds__(256, 2) void gemm_out16(const short* __restrict__ e16,
                                                     const short* __restrict__ wo16,
                                                     const int* __restrict__ idx,
                                                     const float* __restrict__ b_out,
                                                     float* __restrict__ out) {
    __shared__ __align__(16) char smem[65536];   // 2 bufs x (A 16KB | B 16KB)
    const int tid = threadIdx.x;
    const int lane = tid & 63, wid = tid >> 6;
    const int wr = wid >> 1, wc = wid & 1;
    const int l15 = lane & 15, rg = lane >> 4;
    const int bm = blockIdx.x << 7, bn = blockIdx.y << 7;

    const char* eb = (const char*)e16;
    const char* wb = (const char*)wo16;

    // per-thread staging rows: r_i = i*32 + (tid>>3); gather A row index once
    size_t aoff[4];
    #pragma unroll
    for (int i = 0; i < 4; ++i)
        aoff[i] = (size_t)idx[bm + i * 32 + (tid >> 3)] * 512;

#define GO16_STAGE(BUF, KT) do { \
    _Pragma("unroll") for (int i_ = 0; i_ < 4; ++i_) { \
        int u_ = i_ * 256 + tid; \
        int row_ = u_ >> 3, slot_ = u_ & 7; \
        int so_ = ((slot_ ^ (row_ & 7)) << 4); \
        GLOAD16(eb + aoff[i_] + (KT) * 128 + so_, \
                smem + (BUF) * 32768 + u_ * 16); \
        GLOAD16(wb + (size_t)(bn + row_) * 512 + (KT) * 128 + so_, \
                smem + (BUF) * 32768 + 16384 + u_ * 16); \
    } } while (0)

    f32x4 acc[4][4] = {};

    GO16_STAGE(0, 0);
    VMCNT(0);
    __syncthreads();
    #pragma unroll 1
    for (int kt = 0; kt < 4; ++kt) {
        const int buf = kt & 1;
        if (kt + 1 < 4) GO16_STAGE(buf ^ 1, kt + 1);
        const char* aB = smem + buf * 32768 + (wr * 64 + l15) * 128;
        const char* bB = smem + buf * 32768 + 16384 + (wc * 64 + l15) * 128;
        #pragma unroll
        for (int ks = 0; ks < 2; ++ks) {
            const int ax = (((ks * 4 + rg) ^ (l15 & 7)) << 4);
            short8 aF[4], bF[4];
            #pragma unroll
            for (int mi = 0; mi < 4; ++mi) aF[mi] = *(const short8*)(aB + mi * 2048 + ax);
            #pragma unroll
            for (int ni = 0; ni < 4; ++ni) bF[ni] = *(const short8*)(bB + ni * 2048 + ax);
            #pragma unroll
            for (int mi = 0; mi < 4; ++mi)
                #pragma unroll
                for (int ni = 0; ni < 4; ++ni)
                    acc[mi][ni] = __builtin_amdgcn_mfma_f32_16x16x32_f16(aF[mi], bF[ni], acc[mi][ni], 0, 0, 0);
        }
        VMCNT(0);
        __syncthreads();
    }
    float bb[4];
    #pragma unroll
    for (int ni = 0; ni < 4; ++ni) bb[ni] = b_out[bn + wc * 64 + ni * 16 + l15];
    #pragma unroll
    for (int mi = 0; mi < 4; ++mi)
        #pragma unroll
        for (int ni = 0; ni < 4; ++ni)
            #pragma unroll
            for (int j = 0; j < 4; ++j) {
                int r = bm + wr * 64 + mi * 16 + rg * 4 + j;
                int c = bn + wc * 64 + ni * 16 + l15;
                out[(size_t)r * 512 + c] = acc[mi][ni][j] + bb[ni];
            }
}

// =================== fallback f32 path (ws too small) =========================
__global__ __launch_bounds__(256) void esq_kernel(const float* __restrict__ embed,
                                                  float* __restrict__ esq) {
    int wave = threadIdx.x >> 6, lane = threadIdx.x & 63;
    int c = (blockIdx.x << 2) + wave;
    float4 v = reinterpret_cast<const float4*>(embed + (size_t)c * CBD)[lane];
    float s = v.x * v.x + v.y * v.y + v.z * v.z + v.w * v.w;
    #pragma unroll
    for (int m = 32; m; m >>= 1) s += __shfl_xor(s, m, 64);
    if (!lane) esq[c] = s;
}

template <bool GATHER>
__global__ __launch_bounds__(256) void gemm_nt(const float* __restrict__ A,
                                               const float* __restrict__ B,
                                               const float* __restrict__ bias,
                                               const int* __restrict__ gather,
                                               float* __restrict__ C,
                                               int M, int N, int K) {
    __shared__ __align__(16) float sA[64][68];
    __shared__ __align__(16) float sB[64][68];
    const int tid = threadIdx.x;
    const int tx = tid & 15, ty = tid >> 4;
    const int bm = blockIdx.x << 6, bn = blockIdx.y << 6;
    float acc[4][4] = {};
    for (int k0 = 0; k0 < K; k0 += 64) {
        #pragma unroll
        for (int i = 0; i < 4; ++i) {
            int f = tid + (i << 8);
            int m = f >> 4;
            int k4 = (f & 15) << 2;
            long arow = bm + m;
            if (GATHER) arow = gather[arow];
            float4 v = *reinterpret_cast<const float4*>(A + arow * K + k0 + k4);
            sA[k4 + 0][m] = v.x; sA[k4 + 1][m] = v.y;
            sA[k4 + 2][m] = v.z; sA[k4 + 3][m] = v.w;
            float4 w = *reinterpret_cast<const float4*>(B + (long)(bn + m) * K + k0 + k4);
            sB[k4 + 0][m] = w.x; sB[k4 + 1][m] = w.y;
            sB[k4 + 2][m] = w.z; sB[k4 + 3][m] = w.w;
        }
        __syncthreads();
        #pragma unroll
        for (int kk = 0; kk < 64; ++kk) {
            float4 a = *reinterpret_cast<const float4*>(&sA[kk][ty << 2]);
            float4 b = *reinterpret_cast<const float4*>(&sB[kk][tx << 2]);
            float av[4] = {a.x, a.y, a.z, a.w};
            float bv[4] = {b.x, b.y, b.z, b.w};
            #pragma unroll
            for (int i = 0; i < 4; ++i)
                #pragma unroll
                for (int j = 0; j < 4; ++j)
                    acc[i][j] = fmaf(av[i], bv[j], acc[i][j]);
        }
        __syncthreads();
    }
    #pragma unroll
    for (int i = 0; i < 4; ++i) {
        long m = bm + (ty << 2) + i;
        #pragma unroll
        for (int j = 0; j < 4; ++j) {
            int n = bn + (tx << 2) + j;
            C[m * N + n] = acc[i][j] + bias[n];
        }
    }
}

__global__ __launch_bounds__(256) void score_argmax(const float* __restrict__ z,
                                                    const float* __restrict__ embed,
                                                    const float* __restrict__ esq,
                                                    int* __restrict__ idx_out,
                                                    float* __restrict__ idx_f32) {
    __shared__ __align__(16) float sZ[64][68];
    __shared__ __align__(16) float sE[64][68];
    const int tid = threadIdx.x;
    const int tx = tid & 15, ty = tid >> 4;
    const int bm = blockIdx.x << 6;
    float best[4];
    int bidx[4];
    #pragma unroll
    for (int i = 0; i < 4; ++i) { best[i] = -3.4e38f; bidx[i] = 0; }
    for (int ct = 0; ct < CBS; ct += 64) {
        float acc[4][4] = {};
        for (int k0 = 0; k0 < CBD; k0 += 64) {
            #pragma unroll
            for (int i = 0; i < 4; ++i) {
                int f = tid + (i << 8);
                int m = f >> 4;
                int k4 = (f & 15) << 2;
                float4 v = *reinterpret_cast<const float4*>(z + (long)(bm + m) * CBD + k0 + k4);
                sZ[k4 + 0][m] = v.x; sZ[k4 + 1][m] = v.y;
                sZ[k4 + 2][m] = v.z; sZ[k4 + 3][m] = v.w;
                float4 w = *reinterpret_cast<const float4*>(embed + (long)(ct + m) * CBD + k0 + k4);
                sE[k4 + 0][m] = w.x; sE[k4 + 1][m] = w.y;
                sE[k4 + 2][m] = w.z; sE[k4 + 3][m] = w.w;
            }
            __syncthreads();
            #pragma unroll
            for (int kk = 0; kk < 64; ++kk) {
                float4 a = *reinterpret_cast<const float4*>(&sZ[kk][ty << 2]);
                float4 b = *reinterpret_cast<const float4*>(&sE[kk][tx << 2]);
                float av[4] = {a.x, a.y, a.z, a.w};
                float bv[4] = {b.x, b.y, b.z, b.w};
                #pragma unroll
                for (int i = 0; i < 4; ++i)
                    #pragma unroll
                    for (int j = 0; j < 4; ++j)
                        acc[i][j] = fmaf(av[i], bv[j], acc[i][j]);
            }
            __syncthreads();
        }
        #pragma unroll
        for (int j = 0; j < 4; ++j) {
            int c = ct + (tx << 2) + j;
            float eq = esq[c];
            #pragma unroll
            for (int i = 0; i < 4; ++i) {
                float s = 2.0f * acc[i][j] - eq;
                if (s > best[i] || (s == best[i] && c < bidx[i])) { best[i] = s; bidx[i] = c; }
            }
        }
    }
    #pragma unroll
    for (int i = 0; i < 4; ++i) {
        float b = best[i];
        int bi = bidx[i];
        #pragma unroll
        for (int m = 1; m < 16; m <<= 1) {
            float ob = __shfl_xor(b, m, 64);
            int oi = __shfl_xor(bi, m, 64);
            if (ob > b || (ob == b && oi < bi)) { b = ob; bi = oi; }
        }
        if (tx == 0) {
            int row = bm + (ty << 2) + i;
            idx_out[row] = bi;
            idx_f32[row] = (float)bi;
        }
    }
}

extern "C" void kernel_launch(void* const* d_in, const int* in_sizes, int n_in,
                              void* d_out, int out_size, void* d_ws, size_t ws_size,
                              hipStream_t stream) {
    const float* x     = (const float*)d_in[0];
    const float* embed = (const float*)d_in[1];
    const float* W_in  = (const float*)d_in[2];
    const float* b_in  = (const float*)d_in[3];
    const float* W_out = (const float*)d_in[4];
    const float* b_out = (const float*)d_in[5];

    float* out_idx = (float*)d_out;              // [16384] indices as float
    float* out     = (float*)d_out + N_TOK;      // [16384,512]

    // workspace layout (main path). tmax/cand alias xpack (dead after gemm_in).
    char* ws = (char*)d_ws;
    float*  esq      = (float*)ws;                                   // 32KB
    float*  rescueT  = (float*)(ws + 32768);                         // 64KB
    int*    idx      = (int*)(ws + 98304);                           // 64KB
    float2* znorm2   = (float2*)(ws + 163840);                       // 128KB
    float*  denorm   = (float*)(ws + 294912);                        // 32KB
    float*  maxe     = (float*)(ws + 327680);                        // 256B
    short*  xpack    = (short*)(ws + 327936);                        // 33.55MB
    float*  tmax     = (float*)(ws + 327936);                        // 4MB (alias)
    float4* cand     = (float4*)(ws + 327936 + 4194304);             // 1MB (alias)
    float*  zf32     = (float*)(ws + 327936 + 33554432);             // 16.78MB
    short*  z16      = (short*)((char*)zf32 + 16777216);             // 8.39MB
    short*  e16      = z16 + (size_t)N_TOK * 256;                    // 4.19MB
    short*  wo16     = e16 + (size_t)CBS * 256;                      // 0.26MB
    short*  winpk    = wo16 + (size_t)DIM * 256;                     // 0.52MB
    size_t need = (size_t)((char*)(winpk + (size_t)CBD * 1024) - ws);

    if (ws_size >= need) {
        pack_w<9><<<(N_TOK * DIM) / 256, 256, 0, stream>>>(x, xpack);
        pack_w<9><<<(CBD * DIM) / 256, 256, 0, stream>>>(W_in, winpk);
        pack_h<<<(DIM * CBD) / 256, 256, 0, stream>>>(W_out, wo16);
        prep_embed<<<CBS / 4, 256, 0, stream>>>(embed, esq, e16, denorm);
        maxe_k<<<1, 256, 0, stream>>>(esq, denorm, maxe);
        // z = x@W_in^T + b_in (4-term MFMA) -> z16 (f16) + zf32 (exact)
        gemm_in_mfma<<<dim3(N_TOK / 64, 2), 256, 0, stream>>>(xpack, winpk, b_in, z16, zf32);
        znorm_k<<<N_TOK / 4, 256, 0, stream>>>(zf32, z16, znorm2);
        // fp16 scores: running top-2 + LDS-staged esq + breadth-first tile max
        score_mfma<<<512, 256, 0, stream>>>(z16, e16, esq, tmax, cand);
        // combine 4 group candidates -> idx + measured-norm rescue thresholds
        combine<<<N_TOK / 256, 256, 0, stream>>>(cand, znorm2, maxe, idx, out_idx, rescueT);
        // exact rescue (zf32-based; tmax screening; coalesced scan)
        rescue<<<N_TOK, 256, 0, stream>>>(zf32, embed, esq, tmax, rescueT, idx, out_idx);
        // out = e16[idx]@wout16^T + b_out (1-term fp16, 4 slots)
        gemm_out16<<<dim3(N_TOK / 128, 4), 256, 0, stream>>>(e16, wo16, idx, b_out, out);
    } else {
        float* z   = (float*)d_ws;
        float* es  = z + (size_t)N_TOK * CBD;
        int*   id  = (int*)(es + CBS);
        gemm_nt<false><<<dim3(N_TOK / 64, CBD / 64), 256, 0, stream>>>(
            x, W_in, b_in, nullptr, z, N_TOK, CBD, DIM);
        esq_kernel<<<CBS / 4, 256, 0, stream>>>(embed, es);
        score_argmax<<<N_TOK / 64, 256, 0, stream>>>(z, embed, es, id, out_idx);
        gemm_nt<true><<<dim3(N_TOK / 64, DIM / 64), 256, 0, stream>>>(
            embed, W_out, b_out, id, out, N_TOK, DIM, CBD);
    }
}

// Round 20
// 222.801 us; speedup vs baseline: 1.2557x; 1.0223x over previous
//
#include <hip/hip_runtime.h>

#define N_TOK 16384   // B*T = 8*2048
#define DIM   512
#define CBD   256     // codebook dim
#define CBS   8192    // codebook size

typedef short short8 __attribute__((ext_vector_type(8)));
typedef float f32x4 __attribute__((ext_vector_type(4)));

#define GLOAD16(g, l) __builtin_amdgcn_global_load_lds( \
    (const __attribute__((address_space(1))) void*)(g), \
    (__attribute__((address_space(3))) void*)(l), 16, 0, 0)

#define VMCNT(n) asm volatile("s_waitcnt vmcnt(" #n ")" ::: "memory")

__device__ inline unsigned short f2bf_rne(float f) {
    unsigned u = __float_as_uint(f);
    unsigned r = (u + 0x7FFFu + ((u >> 16) & 1u)) >> 16;
    return (unsigned short)r;
}
__device__ inline float bf2f(unsigned short h) { return __uint_as_float((unsigned)h << 16); }
__device__ inline short f2h(float f) {
    _Float16 h = (_Float16)f;           // v_cvt_f16_f32, RNE
    short r; __builtin_memcpy(&r, &h, 2); return r;
}
__device__ inline float h2f(short s) {
    _Float16 h; __builtin_memcpy(&h, &s, 2); return (float)h;
}

// ================= packing: 2-term split [hi(K) | lo(K)] per row ==============
template <int LOGK>
__global__ __launch_bounds__(256) void pack_w(const float* __restrict__ src, short* __restrict__ dst) {
    int e = blockIdx.x * 256 + threadIdx.x;
    int r = e >> LOGK, k = e & ((1 << LOGK) - 1);
    float v = src[e];
    unsigned short h = f2bf_rne(v);
    unsigned short l = f2bf_rne(v - bf2f(h));
    size_t base = (size_t)r << (LOGK + 1);
    dst[base + k] = (short)h;
    dst[base + (1 << LOGK) + k] = (short)l;
}

// ---- 1-term fp16 pack (for W_out) ----
__global__ __launch_bounds__(256) void pack_h(const float* __restrict__ src, short* __restrict__ dst) {
    int e = blockIdx.x * 256 + threadIdx.x;
    dst[e] = f2h(src[e]);
}

// fused: e_sq + f16 pack (score + gemm_out A) + ||e-e16||^2
__global__ __launch_bounds__(256) void prep_embed(const float* __restrict__ embed,
                                                  float* __restrict__ esq,
                                                  short* __restrict__ e16,
                                                  float* __restrict__ denorm) {
    int wave = threadIdx.x >> 6, lane = threadIdx.x & 63;
    int c = (blockIdx.x << 2) + wave;
    float4 v = reinterpret_cast<const float4*>(embed + (size_t)c * CBD)[lane];
    short4 fs;
    fs.x = f2h(v.x); fs.y = f2h(v.y); fs.z = f2h(v.z); fs.w = f2h(v.w);
    reinterpret_cast<short4*>(e16 + (size_t)c * 256)[lane] = fs;
    float s = v.x * v.x + v.y * v.y + v.z * v.z + v.w * v.w;
    float dx = v.x - h2f(fs.x), dy = v.y - h2f(fs.y);
    float dz = v.z - h2f(fs.z), dw = v.w - h2f(fs.w);
    float ds = dx * dx + dy * dy + dz * dz + dw * dw;
    #pragma unroll
    for (int m = 32; m; m >>= 1) { s += __shfl_xor(s, m, 64); ds += __shfl_xor(ds, m, 64); }
    if (!lane) { esq[c] = s; denorm[c] = ds; }
}

// ---- znorm2[r] = (||z16||, ||zf32 - z16||) ----
__global__ __launch_bounds__(256) void znorm_k(const float* __restrict__ zf32,
                                               const short* __restrict__ z16,
                                               float2* __restrict__ znorm2) {
    int wave = threadIdx.x >> 6, lane = threadIdx.x & 63;
    int r = blockIdx.x * 4 + wave;
    float4 v = reinterpret_cast<const float4*>(zf32 + (size_t)r * 256)[lane];
    short4 h = reinterpret_cast<const short4*>(z16 + (size_t)r * 256)[lane];
    float a = h2f(h.x), b = h2f(h.y), c = h2f(h.z), d = h2f(h.w);
    float s16 = a * a + b * b + c * c + d * d;
    float dx = v.x - a, dy = v.y - b, dz = v.z - c, dw = v.w - d;
    float ds = dx * dx + dy * dy + dz * dz + dw * dw;
    #pragma unroll
    for (int m = 32; m; m >>= 1) { s16 += __shfl_xor(s16, m, 64); ds += __shfl_xor(ds, m, 64); }
    if (!lane) znorm2[r] = make_float2(sqrtf(s16), sqrtf(ds));
}

// ---- maxe[0] = max_c ||e_c||, maxe[1] = max_c ||e_c - e16_c|| ----
__global__ __launch_bounds__(256) void maxe_k(const float* __restrict__ esq,
                                              const float* __restrict__ denorm,
                                              float* __restrict__ maxe) {
    float m = 0.f, md = 0.f;
    #pragma unroll
    for (int k = 0; k < 32; ++k) {
        m = fmaxf(m, esq[threadIdx.x + (k << 8)]);
        md = fmaxf(md, denorm[threadIdx.x + (k << 8)]);
    }
    #pragma unroll
    for (int s = 32; s; s >>= 1) {
        m = fmaxf(m, __shfl_xor(m, s, 64));
        md = fmaxf(md, __shfl_xor(md, s, 64));
    }
    __shared__ float w[4], wd[4];
    if (!(threadIdx.x & 63)) { w[threadIdx.x >> 6] = m; wd[threadIdx.x >> 6] = md; }
    __syncthreads();
    if (threadIdx.x == 0) {
        maxe[0] = sqrtf(fmaxf(fmaxf(w[0], w[1]), fmaxf(w[2], w[3])));
        maxe[1] = sqrtf(fmaxf(fmaxf(wd[0], wd[1]), fmaxf(wd[2], wd[3])));
    }
}

// ============ gemm_in: z = x@W_in^T + b_in, 3-term split-bf16, BM=64 BN=128 ===
// kt mapping: 0-7 xh*wh, 8-15 xh*wl, 16-23 xl*wh (the xl*wl term kt24-31 is
// dropped: |sum xl*wl| <= ||xl||*||wl|| ~ 9e-5 << 0.02 rescue slack).
__global__ __launch_bounds__(256, 3) void gemm_in_mfma(const short* __restrict__ xpk,
                                                       const short* __restrict__ wpk,
                                                       const float* __restrict__ b_in,
                                                       short* __restrict__ z16,
                                                       float* __restrict__ zf32) {
    __shared__ __align__(16) char smem[49152];
    const int tid = threadIdx.x;
    const int lane = tid & 63, wid = tid >> 6;
    const int l15 = lane & 15, rg = lane >> 4;
    const int bm = blockIdx.x << 6, bn = blockIdx.y << 7;
    const int g = tid & 7, rpb = tid >> 3;

    const char* xb = (const char*)xpk;
    const char* wb = (const char*)wpk;
    const int sw = ((g ^ (rpb & 7)) << 4);
    size_t aoff[2], boff[2][2];
    #pragma unroll
    for (int it = 0; it < 2; ++it)
        aoff[it] = (size_t)(bm + it * 32 + rpb) * 2048 + sw;
    #pragma unroll
    for (int it = 0; it < 4; ++it)
        boff[it >> 1][it & 1] = (size_t)(bn + it * 32 + rpb) * 2048 + sw;

    const int ax0 = ((rg ^ (l15 & 7)) << 4);
    const int ax1 = (((rg + 4) ^ (l15 & 7)) << 4);
    const char* aBase = smem + l15 * 128;
    const char* bBase = smem + 8192 + (wid * 32 + l15) * 128;

    f32x4 acc[4][2] = {};

#define GIN_STAGE(BUF, KT) do { \
    size_t aK = (size_t)(((((KT) >> 4) << 3) | ((KT) & 7))) * 128; \
    size_t bK = (size_t)((((((KT) >> 3) & 1) << 3) | ((KT) & 7))) * 128; \
    char* dA = smem + (BUF) * 24576 + (tid << 4); \
    char* dB = dA + 8192; \
    GLOAD16(xb + aoff[0] + aK, dA); \
    GLOAD16(xb + aoff[1] + aK, dA + 4096); \
    GLOAD16(wb + boff[0][0] + bK, dB); \
    GLOAD16(wb + boff[0][1] + bK, dB + 4096); \
    GLOAD16(wb + boff[1][0] + bK, dB + 8192); \
    GLOAD16(wb + boff[1][1] + bK, dB + 12288); } while (0)

    GIN_STAGE(0, 0);
    VMCNT(0);
    __syncthreads();
    #pragma unroll 1
    for (int kt = 0; kt < 24; ++kt) {
        const int buf = kt & 1;
        if (kt + 1 < 24) GIN_STAGE(buf ^ 1, kt + 1);
        const char* aB = aBase + buf * 24576;
        const char* bB = bBase + buf * 24576;
        #pragma unroll
        for (int ks = 0; ks < 2; ++ks) {
            int ax = ks ? ax1 : ax0;
            short8 aF[4], bF[2];
            #pragma unroll
            for (int mi = 0; mi < 4; ++mi) aF[mi] = *(const short8*)(aB + mi * 2048 + ax);
            #pragma unroll
            for (int ni = 0; ni < 2; ++ni) bF[ni] = *(const short8*)(bB + ni * 2048 + ax);
            #pragma unroll
            for (int mi = 0; mi < 4; ++mi)
                #pragma unroll
                for (int ni = 0; ni < 2; ++ni)
                    acc[mi][ni] = __builtin_amdgcn_mfma_f32_16x16x32_bf16(aF[mi], bF[ni], acc[mi][ni], 0, 0, 0);
        }
        VMCNT(0);
        __syncthreads();
    }
    float bb[2];
    #pragma unroll
    for (int ni = 0; ni < 2; ++ni) bb[ni] = b_in[bn + wid * 32 + ni * 16 + l15];
    #pragma unroll
    for (int mi = 0; mi < 4; ++mi)
        #pragma unroll
        for (int ni = 0; ni < 2; ++ni)
            #pragma unroll
            for (int j = 0; j < 4; ++j) {
                int r = bm + mi * 16 + rg * 4 + j;
                int c = bn + wid * 32 + ni * 16 + l15;
                float s = acc[mi][ni][j] + bb[ni];
                z16[(size_t)r * 256 + c] = f2h(s);
                zf32[(size_t)r * 256 + c] = s;
            }
}

// ===== score: A-in-registers (static idx), half-K B chunks, 2 blocks/CU.
// Running per-lane top-2; per-tile MAX breadth-first -> tmax; esq in LDS ring;
// ONE full merge per block -> cand.
__global__ __launch_bounds__(256, 2) void score_mfma(const short* __restrict__ zpk,
                                                     const short* __restrict__ epk,
                                                     const float* __restrict__ esqg,
                                                     float* __restrict__ tmax,
                                                     float4* __restrict__ cand) {
    __shared__ __align__(16) char smem[67584];   // B: 2x32KB | esq ring 2x1KB @65536
    const int tid = threadIdx.x;
    const int lane = tid & 63, w = tid >> 6;     // 4 waves
    const int l15 = lane & 15, rg = lane >> 4;

    int flat = blockIdx.x;                       // 512 blocks
    int xcd = flat & 7, jb = flat >> 3;          // jb 0..63
    int g  = xcd >> 1;                           // col-group 0..3 (XCD pair)
    int bX = ((xcd & 1) << 6) + jb;              // 0..127 row-block (128 rows)
    const int bm = bX << 7;
    const int C0g = g << 11;                     // g*2048

    const char* zb = (const char*)zpk;
    short8 aF0[8], aF1[8];
    #pragma unroll
    for (int ks = 0; ks < 8; ++ks) {
        aF0[ks] = *(const short8*)(zb + (size_t)(bm + w * 32 + l15) * 512 + ks * 64 + rg * 16);
        aF1[ks] = *(const short8*)(zb + (size_t)(bm + w * 32 + 16 + l15) * 512 + ks * 64 + rg * 16);
    }

    const char* eb = (const char*)epk;

#define SCB_STAGE(BUF, T, H) do { \
    _Pragma("unroll") for (int i_ = 0; i_ < 8; ++i_) { \
        int u_ = i_ * 256 + tid; \
        int col_ = u_ >> 4, slot_ = u_ & 15; \
        const char* s_ = eb + (size_t)(C0g + (T) * 128 + col_) * 512 + (H) * 256 \
                         + ((slot_ ^ (col_ & 15)) << 4); \
        GLOAD16(s_, smem + (BUF) * 32768 + u_ * 16); \
    } } while (0)

#define SCE_STAGE(T) do { \
    if (w == 0) { \
        const char* s_ = (const char*)esqg + (size_t)(C0g + (T) * 128) * 4 + lane * 16; \
        GLOAD16(s_, smem + 65536 + (((T) & 1) << 10) + lane * 16); \
    } } while (0)

#define SC_PHASE(BUF, KS0) do { \
    const char* bB = smem + (BUF) * 32768; \
    _Pragma("unroll") for (int ksl = 0; ksl < 4; ++ksl) { \
        short8 bF[8]; \
        _Pragma("unroll") for (int ni = 0; ni < 8; ++ni) \
            bF[ni] = *(const short8*)(bB + (ni * 16 + l15) * 256 + \
                                      (((ksl * 4 + rg) ^ (l15 & 15)) << 4)); \
        _Pragma("unroll") for (int ni = 0; ni < 8; ++ni) { \
            acc0[ni] = __builtin_amdgcn_mfma_f32_16x16x32_f16(aF0[(KS0) + ksl], bF[ni], acc0[ni], 0, 0, 0); \
            acc1[ni] = __builtin_amdgcn_mfma_f32_16x16x32_f16(aF1[(KS0) + ksl], bF[ni], acc1[ni], 0, 0, 0); \
        } \
    } } while (0)

    f32x4 acc0[8] = {};
    f32x4 acc1[8] = {};
    float rv1[2][4], rv2[2][4];
    int   ri1[2][4];
    #pragma unroll
    for (int mi = 0; mi < 2; ++mi)
        #pragma unroll
        for (int j2 = 0; j2 < 4; ++j2) {
            rv1[mi][j2] = -3.4e38f; rv2[mi][j2] = -3.4e38f; ri1[mi][j2] = 0x7fffffff;
        }

    SCB_STAGE(0, 0, 0);
    SCE_STAGE(0);
    VMCNT(0);
    __syncthreads();

    #pragma unroll 1
    for (int t = 0; t < 16; ++t) {
        SCB_STAGE(1, t, 1);
        SC_PHASE(0, 0);
        VMCNT(0);
        __syncthreads();
        if (t < 15) { SCB_STAGE(0, t + 1, 0); SCE_STAGE(t + 1); }
        SC_PHASE(1, 4);
        {
            const char* eL = smem + 65536 + ((t & 1) << 10);
            float esq8[8];
            #pragma unroll
            for (int ni = 0; ni < 8; ++ni)
                esq8[ni] = *(const float*)(eL + (ni * 16 + l15) * 4);
            float tm[2][4];
            #pragma unroll
            for (int mi = 0; mi < 2; ++mi)
                #pragma unroll
                for (int j2 = 0; j2 < 4; ++j2) {
                    float tmx = -3.4e38f;
                    #pragma unroll
                    for (int ni = 0; ni < 8; ++ni) {
                        float s = fmaf(2.f, mi ? acc1[ni][j2] : acc0[ni][j2], -esq8[ni]);
                        int c = C0g + t * 128 + l15 + ni * 16;
                        if (s > rv1[mi][j2]) { rv2[mi][j2] = rv1[mi][j2]; rv1[mi][j2] = s; ri1[mi][j2] = c; }
                        else if (s > rv2[mi][j2]) rv2[mi][j2] = s;
                        tmx = fmaxf(tmx, s);
                    }
                    tm[mi][j2] = tmx;
                }
            #pragma unroll
            for (int m = 1; m < 16; m <<= 1)
                #pragma unroll
                for (int mi = 0; mi < 2; ++mi)
                    #pragma unroll
                    for (int j2 = 0; j2 < 4; ++j2)
                        tm[mi][j2] = fmaxf(tm[mi][j2], __shfl_xor(tm[mi][j2], m, 64));
            if (l15 == 0) {
                #pragma unroll
                for (int mi = 0; mi < 2; ++mi)
                    #pragma unroll
                    for (int j2 = 0; j2 < 4; ++j2) {
                        int row = bm + w * 32 + mi * 16 + rg * 4 + j2;
                        tmax[(size_t)(g * 16 + t) * N_TOK + row] = tm[mi][j2];
                    }
            }
            #pragma unroll
            for (int ni = 0; ni < 8; ++ni) {
                acc0[ni] = (f32x4){0.f, 0.f, 0.f, 0.f};
                acc1[ni] = (f32x4){0.f, 0.f, 0.f, 0.f};
            }
        }
        VMCNT(0);
        __syncthreads();
    }

    #pragma unroll
    for (int mi = 0; mi < 2; ++mi)
        #pragma unroll
        for (int j2 = 0; j2 < 4; ++j2) {
            float v1 = rv1[mi][j2], v2 = rv2[mi][j2];
            int i1 = ri1[mi][j2];
            #pragma unroll
            for (int m = 1; m < 16; m <<= 1) {
                float ov1 = __shfl_xor(v1, m, 64);
                int   oi1 = __shfl_xor(i1, m, 64);
                float ov2 = __shfl_xor(v2, m, 64);
                float nv2 = fmaxf(fmaxf(v2, ov2), fminf(v1, ov1));
                if (ov1 > v1 || (ov1 == v1 && oi1 < i1)) { v1 = ov1; i1 = oi1; }
                v2 = nv2;
            }
            if (l15 == 0) {
                int row = bm + w * 32 + mi * 16 + rg * 4 + j2;
                cand[(size_t)g * N_TOK + row] = make_float4(v1, __int_as_float(i1), v2, 0.f);
            }
        }
}

// -------- combine: merge 4 group candidates + measured-norm rescue decision ---
__global__ __launch_bounds__(256) void combine(const float4* __restrict__ cand,
                                               const float2* __restrict__ znorm2,
                                               const float* __restrict__ maxe,
                                               int* __restrict__ idx, float* __restrict__ idxf,
                                               float* __restrict__ rescueT) {
    int row = blockIdx.x * 256 + threadIdx.x;
    float4 p = cand[row];
    float v1 = p.x; int i1 = __float_as_int(p.y); float v2 = p.z;
    #pragma unroll
    for (int g = 1; g < 4; ++g) {
        float4 q = cand[(size_t)g * N_TOK + row];
        float w1 = q.x; int jx = __float_as_int(q.y);
        float nv2 = fmaxf(fmaxf(v2, q.z), fminf(v1, w1));
        if (w1 > v1 || (w1 == v1 && jx < i1)) { v1 = w1; i1 = jx; }
        v2 = nv2;
    }
    float2 zn = znorm2[row];
    float thr = fmaf(2.1f, zn.y * maxe[0] + zn.x * maxe[1], 0.02f);
    idx[row] = i1;
    idxf[row] = (float)i1;
    rescueT[row] = (v1 - v2 <= thr) ? (v1 - thr) : 3.0e38f;
}

// ---- exact rescue: tmax screening; 16 lanes per code (coalesced) f32 rescan ---
__global__ __launch_bounds__(256) void rescue(const float* __restrict__ zf32,
                                              const float* __restrict__ embed,
                                              const float* __restrict__ esq,
                                              const float* __restrict__ tmax,
                                              const float* __restrict__ rescueT,
                                              int* __restrict__ idx, float* __restrict__ idxf) {
    int row = blockIdx.x;
    float t = rescueT[row];
    if (t > 1.0e38f) return;
    __shared__ __align__(16) float zrow[256];
    __shared__ float gv[16];
    __shared__ int   gi[16];
    const int tid = threadIdx.x;
    const int grp = tid >> 4, ln = tid & 15;
    zrow[tid] = zf32[(size_t)row * 256 + tid];
    __syncthreads();
    const float4* zr = (const float4*)zrow;
    float bv = -3.4e38f; int bi = 0x7fffffff;
    for (int nt = 0; nt < 64; ++nt) {
        if (tmax[(size_t)nt * N_TOK + row] < t) continue;  // block-uniform
        #pragma unroll 1
        for (int it = 0; it < 8; ++it) {
            int c = nt * 128 + it * 16 + grp;
            const float4* er = (const float4*)(embed + (size_t)c * 256);
            float d = 0.f;
            #pragma unroll
            for (int q = 0; q < 4; ++q) {
                float4 e4 = er[q * 16 + ln];
                float4 z4 = zr[q * 16 + ln];
                d = fmaf(e4.x, z4.x, d); d = fmaf(e4.y, z4.y, d);
                d = fmaf(e4.z, z4.z, d); d = fmaf(e4.w, z4.w, d);
            }
            #pragma unroll
            for (int m = 1; m < 16; m <<= 1) d += __shfl_xor(d, m, 64);
            if (ln == 0) {
                float s = 2.f * d - esq[c];
                if (s > bv || (s == bv && c < bi)) { bv = s; bi = c; }
            }
        }
    }
    if (ln == 0) { gv[grp] = bv; gi[grp] = bi; }
    __syncthreads();
    if (tid == 0) {
        float v = gv[0]; int i = gi[0];
        #pragma unroll
        for (int k = 1; k < 16; ++k)
            if (gv[k] > v || (gv[k] == v && gi[k] < i)) { v = gv[k]; i = gi[k]; }
        idx[row] = i; idxf[row] = (float)i;
    }
}

// ====== gemm_out16: out = e16[idx]@wout16^T + b_out, 1-term fp16, BM=128 BN=128
__global__ __launch_bounds__(256, 2) void gemm_out16(const short* __restrict__ e16,
                                                     const short* __restrict__ wo16,
                                                     const int* __restrict__ idx,
                                                     const float* __restrict__ b_out,
                                                     float* __restrict__ out) {
    __shared__ __align__(16) char smem[65536];   // 2 bufs x (A 16KB | B 16KB)
    const int tid = threadIdx.x;
    const int lane = tid & 63, wid = tid >> 6;
    const int wr = wid >> 1, wc = wid & 1;
    const int l15 = lane & 15, rg = lane >> 4;
    const int bm = blockIdx.x << 7, bn = blockIdx.y << 7;

    const char* eb = (const char*)e16;
    const char* wb = (const char*)wo16;

    size_t aoff[4];
    #pragma unroll
    for (int i = 0; i < 4; ++i)
        aoff[i] = (size_t)idx[bm + i * 32 + (tid >> 3)] * 512;

#define GO16_STAGE(BUF, KT) do { \
    _Pragma("unroll") for (int i_ = 0; i_ < 4; ++i_) { \
        int u_ = i_ * 256 + tid; \
        int row_ = u_ >> 3, slot_ = u_ & 7; \
        int so_ = ((slot_ ^ (row_ & 7)) << 4); \
        GLOAD16(eb + aoff[i_] + (KT) * 128 + so_, \
                smem + (BUF) * 32768 + u_ * 16); \
        GLOAD16(wb + (size_t)(bn + row_) * 512 + (KT) * 128 + so_, \
                smem + (BUF) * 32768 + 16384 + u_ * 16); \
    } } while (0)

    f32x4 acc[4][4] = {};

    GO16_STAGE(0, 0);
    VMCNT(0);
    __syncthreads();
    #pragma unroll 1
    for (int kt = 0; kt < 4; ++kt) {
        const int buf = kt & 1;
        if (kt + 1 < 4) GO16_STAGE(buf ^ 1, kt + 1);
        const char* aB = smem + buf * 32768 + (wr * 64 + l15) * 128;
        const char* bB = smem + buf * 32768 + 16384 + (wc * 64 + l15) * 128;
        #pragma unroll
        for (int ks = 0; ks < 2; ++ks) {
            const int ax = (((ks * 4 + rg) ^ (l15 & 7)) << 4);
            short8 aF[4], bF[4];
            #pragma unroll
            for (int mi = 0; mi < 4; ++mi) aF[mi] = *(const short8*)(aB + mi * 2048 + ax);
            #pragma unroll
            for (int ni = 0; ni < 4; ++ni) bF[ni] = *(const short8*)(bB + ni * 2048 + ax);
            #pragma unroll
            for (int mi = 0; mi < 4; ++mi)
                #pragma unroll
                for (int ni = 0; ni < 4; ++ni)
                    acc[mi][ni] = __builtin_amdgcn_mfma_f32_16x16x32_f16(aF[mi], bF[ni], acc[mi][ni], 0, 0, 0);
        }
        VMCNT(0);
        __syncthreads();
    }
    float bb[4];
    #pragma unroll
    for (int ni = 0; ni < 4; ++ni) bb[ni] = b_out[bn + wc * 64 + ni * 16 + l15];
    #pragma unroll
    for (int mi = 0; mi < 4; ++mi)
        #pragma unroll
        for (int ni = 0; ni < 4; ++ni)
            #pragma unroll
            for (int j = 0; j < 4; ++j) {
                int r = bm + wr * 64 + mi * 16 + rg * 4 + j;
                int c = bn + wc * 64 + ni * 16 + l15;
                out[(size_t)r * 512 + c] = acc[mi][ni][j] + bb[ni];
            }
}

// =================== fallback f32 path (ws too small) =========================
__global__ __launch_bounds__(256) void esq_kernel(const float* __restrict__ embed,
                                                  float* __restrict__ esq) {
    int wave = threadIdx.x >> 6, lane = threadIdx.x & 63;
    int c = (blockIdx.x << 2) + wave;
    float4 v = reinterpret_cast<const float4*>(embed + (size_t)c * CBD)[lane];
    float s = v.x * v.x + v.y * v.y + v.z * v.z + v.w * v.w;
    #pragma unroll
    for (int m = 32; m; m >>= 1) s += __shfl_xor(s, m, 64);
    if (!lane) esq[c] = s;
}

template <bool GATHER>
__global__ __launch_bounds__(256) void gemm_nt(const float* __restrict__ A,
                                               const float* __restrict__ B,
                                               const float* __restrict__ bias,
                                               const int* __restrict__ gather,
                                               float* __restrict__ C,
                                               int M, int N, int K) {
    __shared__ __align__(16) float sA[64][68];
    __shared__ __align__(16) float sB[64][68];
    const int tid = threadIdx.x;
    const int tx = tid & 15, ty = tid >> 4;
    const int bm = blockIdx.x << 6, bn = blockIdx.y << 6;
    float acc[4][4] = {};
    for (int k0 = 0; k0 < K; k0 += 64) {
        #pragma unroll
        for (int i = 0; i < 4; ++i) {
            int f = tid + (i << 8);
            int m = f >> 4;
            int k4 = (f & 15) << 2;
            long arow = bm + m;
            if (GATHER) arow = gather[arow];
            float4 v = *reinterpret_cast<const float4*>(A + arow * K + k0 + k4);
            sA[k4 + 0][m] = v.x; sA[k4 + 1][m] = v.y;
            sA[k4 + 2][m] = v.z; sA[k4 + 3][m] = v.w;
            float4 w = *reinterpret_cast<const float4*>(B + (long)(bn + m) * K + k0 + k4);
            sB[k4 + 0][m] = w.x; sB[k4 + 1][m] = w.y;
            sB[k4 + 2][m] = w.z; sB[k4 + 3][m] = w.w;
        }
        __syncthreads();
        #pragma unroll
        for (int kk = 0; kk < 64; ++kk) {
            float4 a = *reinterpret_cast<const float4*>(&sA[kk][ty << 2]);
            float4 b = *reinterpret_cast<const float4*>(&sB[kk][tx << 2]);
            float av[4] = {a.x, a.y, a.z, a.w};
            float bv[4] = {b.x, b.y, b.z, b.w};
            #pragma unroll
            for (int i = 0; i < 4; ++i)
                #pragma unroll
                for (int j = 0; j < 4; ++j)
                    acc[i][j] = fmaf(av[i], bv[j], acc[i][j]);
        }
        __syncthreads();
    }
    #pragma unroll
    for (int i = 0; i < 4; ++i) {
        long m = bm + (ty << 2) + i;
        #pragma unroll
        for (int j = 0; j < 4; ++j) {
            int n = bn + (tx << 2) + j;
            C[m * N + n] = acc[i][j] + bias[n];
        }
    }
}

__global__ __launch_bounds__(256) void score_argmax(const float* __restrict__ z,
                                                    const float* __restrict__ embed,
                                                    const float* __restrict__ esq,
                                                    int* __restrict__ idx_out,
                                                    float* __restrict__ idx_f32) {
    __shared__ __align__(16) float sZ[64][68];
    __shared__ __align__(16) float sE[64][68];
    const int tid = threadIdx.x;
    const int tx = tid & 15, ty = tid >> 4;
    const int bm = blockIdx.x << 6;
    float best[4];
    int bidx[4];
    #pragma unroll
    for (int i = 0; i < 4; ++i) { best[i] = -3.4e38f; bidx[i] = 0; }
    for (int ct = 0; ct < CBS; ct += 64) {
        float acc[4][4] = {};
        for (int k0 = 0; k0 < CBD; k0 += 64) {
            #pragma unroll
            for (int i = 0; i < 4; ++i) {
                int f = tid + (i << 8);
                int m = f >> 4;
                int k4 = (f & 15) << 2;
                float4 v = *reinterpret_cast<const float4*>(z + (long)(bm + m) * CBD + k0 + k4);
                sZ[k4 + 0][m] = v.x; sZ[k4 + 1][m] = v.y;
                sZ[k4 + 2][m] = v.z; sZ[k4 + 3][m] = v.w;
                float4 w = *reinterpret_cast<const float4*>(embed + (long)(ct + m) * CBD + k0 + k4);
                sE[k4 + 0][m] = w.x; sE[k4 + 1][m] = w.y;
                sE[k4 + 2][m] = w.z; sE[k4 + 3][m] = w.w;
            }
            __syncthreads();
            #pragma unroll
            for (int kk = 0; kk < 64; ++kk) {
                float4 a = *reinterpret_cast<const float4*>(&sZ[kk][ty << 2]);
                float4 b = *reinterpret_cast<const float4*>(&sE[kk][tx << 2]);
                float av[4] = {a.x, a.y, a.z, a.w};
                float bv[4] = {b.x, b.y, b.z, b.w};
                #pragma unroll
                for (int i = 0; i < 4; ++i)
                    #pragma unroll
                    for (int j = 0; j < 4; ++j)
                        acc[i][j] = fmaf(av[i], bv[j], acc[i][j]);
            }
            __syncthreads();
        }
        #pragma unroll
        for (int j = 0; j < 4; ++j) {
            int c = ct + (tx << 2) + j;
            float eq = esq[c];
            #pragma unroll
            for (int i = 0; i < 4; ++i) {
                float s = 2.0f * acc[i][j] - eq;
                if (s > best[i] || (s == best[i] && c < bidx[i])) { best[i] = s; bidx[i] = c; }
            }
        }
    }
    #pragma unroll
    for (int i = 0; i < 4; ++i) {
        float b = best[i];
        int bi = bidx[i];
        #pragma unroll
        for (int m = 1; m < 16; m <<= 1) {
            float ob = __shfl_xor(b, m, 64);
            int oi = __shfl_xor(bi, m, 64);
            if (ob > b || (ob == b && oi < bi)) { b = ob; bi = oi; }
        }
        if (tx == 0) {
            int row = bm + (ty << 2) + i;
            idx_out[row] = bi;
            idx_f32[row] = (float)bi;
        }
    }
}

extern "C" void kernel_launch(void* const* d_in, const int* in_sizes, int n_in,
                              void* d_out, int out_size, void* d_ws, size_t ws_size,
                              hipStream_t stream) {
    const float* x     = (const float*)d_in[0];
    const float* embed = (const float*)d_in[1];
    const float* W_in  = (const float*)d_in[2];
    const float* b_in  = (const float*)d_in[3];
    const float* W_out = (const float*)d_in[4];
    const float* b_out = (const float*)d_in[5];

    float* out_idx = (float*)d_out;              // [16384] indices as float
    float* out     = (float*)d_out + N_TOK;      // [16384,512]

    // workspace layout (main path). tmax/cand alias xpack (dead after gemm_in).
    char* ws = (char*)d_ws;
    float*  esq      = (float*)ws;                                   // 32KB
    float*  rescueT  = (float*)(ws + 32768);                         // 64KB
    int*    idx      = (int*)(ws + 98304);                           // 64KB
    float2* znorm2   = (float2*)(ws + 163840);                       // 128KB
    float*  denorm   = (float*)(ws + 294912);                        // 32KB
    float*  maxe     = (float*)(ws + 327680);                        // 256B
    short*  xpack    = (short*)(ws + 327936);                        // 33.55MB
    float*  tmax     = (float*)(ws + 327936);                        // 4MB (alias)
    float4* cand     = (float4*)(ws + 327936 + 4194304);             // 1MB (alias)
    float*  zf32     = (float*)(ws + 327936 + 33554432);             // 16.78MB
    short*  z16      = (short*)((char*)zf32 + 16777216);             // 8.39MB
    short*  e16      = z16 + (size_t)N_TOK * 256;                    // 4.19MB
    short*  wo16     = e16 + (size_t)CBS * 256;                      // 0.26MB
    short*  winpk    = wo16 + (size_t)DIM * 256;                     // 0.52MB
    size_t need = (size_t)((char*)(winpk + (size_t)CBD * 1024) - ws);

    if (ws_size >= need) {
        pack_w<9><<<(N_TOK * DIM) / 256, 256, 0, stream>>>(x, xpack);
        pack_w<9><<<(CBD * DIM) / 256, 256, 0, stream>>>(W_in, winpk);
        pack_h<<<(DIM * CBD) / 256, 256, 0, stream>>>(W_out, wo16);
        prep_embed<<<CBS / 4, 256, 0, stream>>>(embed, esq, e16, denorm);
        maxe_k<<<1, 256, 0, stream>>>(esq, denorm, maxe);
        // z = x@W_in^T + b_in (3-term MFMA) -> z16 (f16) + zf32 (near-exact)
        gemm_in_mfma<<<dim3(N_TOK / 64, 2), 256, 0, stream>>>(xpack, winpk, b_in, z16, zf32);
        znorm_k<<<N_TOK / 4, 256, 0, stream>>>(zf32, z16, znorm2);
        // fp16 scores: running top-2 + LDS-staged esq + breadth-first tile max
        score_mfma<<<512, 256, 0, stream>>>(z16, e16, esq, tmax, cand);
        // combine 4 group candidates -> idx + measured-norm rescue thresholds
        combine<<<N_TOK / 256, 256, 0, stream>>>(cand, znorm2, maxe, idx, out_idx, rescueT);
        // exact rescue (zf32-based; tmax screening; coalesced scan)
        rescue<<<N_TOK, 256, 0, stream>>>(zf32, embed, esq, tmax, rescueT, idx, out_idx);
        // out = e16[idx]@wout16^T + b_out (1-term fp16, 4 slots)
        gemm_out16<<<dim3(N_TOK / 128, 4), 256, 0, stream>>>(e16, wo16, idx, b_out, out);
    } else {
        float* z   = (float*)d_ws;
        float* es  = z + (size_t)N_TOK * CBD;
        int*   id  = (int*)(es + CBS);
        gemm_nt<false><<<dim3(N_TOK / 64, CBD / 64), 256, 0, stream>>>(
            x, W_in, b_in, nullptr, z, N_TOK, CBD, DIM);
        esq_kernel<<<CBS / 4, 256, 0, stream>>>(embed, es);
        score_argmax<<<N_TOK / 64, 256, 0, stream>>>(z, embed, es, id, out_idx);
        gemm_nt<true><<<dim3(N_TOK / 64, DIM / 64), 256, 0, stream>>>(
            embed, W_out, b_out, id, out, N_TOK, DIM, CBD);
    }
}